// Round 1
// baseline (1917.130 us; speedup 1.0000x reference)
//
#include <hip/hip_runtime.h>
#include <hip/hip_bf16.h>
#include <math.h>

typedef unsigned short u16;
typedef __attribute__((ext_vector_type(8))) short short8;
typedef __attribute__((ext_vector_type(4))) float f32x4;

#define E_ 768
#define H_ 12
#define D_ 64
#define C_ 256
#define R_ 32
#define N_ 4
#define F_ 3072
#define T_ 32768   // R_*C_*N_

union U8 { u16 u[8]; short8 v; };

__device__ __forceinline__ u16 f2bf(float f) {
    unsigned u = __builtin_bit_cast(unsigned, f);
    u = (u + 0x7FFFu + ((u >> 16) & 1u)) >> 16;
    return (u16)u;
}
__device__ __forceinline__ float bf2f(u16 h) {
    unsigned u = ((unsigned)h) << 16;
    return __builtin_bit_cast(float, u);
}

// ---------------- fp32 -> bf16 weight convert ----------------
__global__ __launch_bounds__(256) void cvt_kernel(const float* __restrict__ src,
                                                  u16* __restrict__ dst, int n) {
    int i = (blockIdx.x * 256 + threadIdx.x) * 4;
    if (i >= n) return;
    float4 v = *reinterpret_cast<const float4*>(src + i);
    ushort4 o;
    o.x = f2bf(v.x); o.y = f2bf(v.y); o.z = f2bf(v.z); o.w = f2bf(v.w);
    *reinterpret_cast<ushort4*>(dst + i) = o;
}

// ---------------- LayerNorm: one wave per token (E=768) ----------------
__global__ __launch_bounds__(256) void ln_kernel(const float* __restrict__ x,
                                                 const float* __restrict__ w,
                                                 const float* __restrict__ b,
                                                 u16* __restrict__ out) {
    int wid = threadIdx.x >> 6, lane = threadIdx.x & 63;
    size_t t = (size_t)blockIdx.x * 4 + wid;
    const float* xp = x + t * E_;
    float4 v[3];
    float s1 = 0.f, s2 = 0.f;
#pragma unroll
    for (int c = 0; c < 3; c++) {
        v[c] = *reinterpret_cast<const float4*>(xp + c * 256 + lane * 4);
        s1 += v[c].x + v[c].y + v[c].z + v[c].w;
        s2 += v[c].x * v[c].x + v[c].y * v[c].y + v[c].z * v[c].z + v[c].w * v[c].w;
    }
#pragma unroll
    for (int off = 32; off >= 1; off >>= 1) {
        s1 += __shfl_xor(s1, off);
        s2 += __shfl_xor(s2, off);
    }
    float mu = s1 * (1.0f / E_);
    float var = s2 * (1.0f / E_) - mu * mu;
    float inv = rsqrtf(var + 1e-12f);
#pragma unroll
    for (int c = 0; c < 3; c++) {
        int e = c * 256 + lane * 4;
        float4 wv = *reinterpret_cast<const float4*>(w + e);
        float4 bv = *reinterpret_cast<const float4*>(b + e);
        ushort4 o;
        o.x = f2bf((v[c].x - mu) * inv * wv.x + bv.x);
        o.y = f2bf((v[c].y - mu) * inv * wv.y + bv.y);
        o.z = f2bf((v[c].z - mu) * inv * wv.z + bv.z);
        o.w = f2bf((v[c].w - mu) * inv * wv.w + bv.w);
        *reinterpret_cast<ushort4*>(out + t * E_ + e) = o;
    }
}

// ---------------- GEMM: y[m,n] = A[m,:]·W[n,:] + bias ----------------
// MODE 0: store bf16 (optionally GELU). MODE 1: dstF = resid + acc (fp32).
template<int MODE, bool GELU>
__global__ __launch_bounds__(256) void gemm_kernel(
    const u16* __restrict__ A, int lda,
    const u16* __restrict__ W, int ldw,
    const float* __restrict__ bias, int K,
    u16* __restrict__ dstB, int ldd,
    float* __restrict__ dstF, const float* __restrict__ resid) {
    __shared__ u16 As[64][40];
    __shared__ u16 Ws[64][40];
    int tid = threadIdx.x;
    int m0 = blockIdx.y * 64, n0 = blockIdx.x * 64;
    int wid = tid >> 6, lane = tid & 63;
    int wy = wid >> 1, wx = wid & 1;
    int sr = tid >> 2, sc = (tid & 3) * 8;
    const u16* ga = A + (size_t)(m0 + sr) * lda + sc;
    const u16* gw = W + (size_t)(n0 + sr) * ldw + sc;
    int li = lane & 15, ko = (lane >> 4) * 8;

    f32x4 acc[2][2] = {};
    for (int k0 = 0; k0 < K; k0 += 32) {
        *reinterpret_cast<short8*>(&As[sr][sc]) = *reinterpret_cast<const short8*>(ga + k0);
        *reinterpret_cast<short8*>(&Ws[sr][sc]) = *reinterpret_cast<const short8*>(gw + k0);
        __syncthreads();
        short8 af[2], wf[2];
        af[0] = *reinterpret_cast<const short8*>(&As[wy * 32 + li][ko]);
        af[1] = *reinterpret_cast<const short8*>(&As[wy * 32 + 16 + li][ko]);
        wf[0] = *reinterpret_cast<const short8*>(&Ws[wx * 32 + li][ko]);
        wf[1] = *reinterpret_cast<const short8*>(&Ws[wx * 32 + 16 + li][ko]);
#pragma unroll
        for (int mi = 0; mi < 2; mi++)
#pragma unroll
            for (int ni = 0; ni < 2; ni++)
                acc[mi][ni] = __builtin_amdgcn_mfma_f32_16x16x32_bf16(af[mi], wf[ni], acc[mi][ni], 0, 0, 0);
        __syncthreads();
    }
#pragma unroll
    for (int mi = 0; mi < 2; mi++)
#pragma unroll
        for (int ni = 0; ni < 2; ni++) {
            int n = n0 + wx * 32 + ni * 16 + li;
            float bn = bias ? bias[n] : 0.0f;
#pragma unroll
            for (int r = 0; r < 4; r++) {
                int m = m0 + wy * 32 + mi * 16 + (lane >> 4) * 4 + r;
                float vv = acc[mi][ni][r] + bn;
                if (GELU) vv = 0.5f * vv * (1.0f + erff(vv * 0.70710678118654752f));
                if (MODE == 0)
                    dstB[(size_t)m * ldd + n] = f2bf(vv);
                else
                    dstF[(size_t)m * ldd + n] = resid[(size_t)m * ldd + n] + vv;
            }
        }
}

// ---------------- Row-attention scores: aw[h,n,i,j] = s * sum_{r,d} q·k ----------------
__global__ __launch_bounds__(256) void row_scores_kernel(const u16* __restrict__ q,
                                                         const u16* __restrict__ k,
                                                         float* __restrict__ aw) {
    int tile = blockIdx.x;            // 16: 4 i-tiles x 4 j-tiles
    int hn = blockIdx.y;              // 48
    int h = hn >> 2, n = hn & 3;
    int i0 = (tile >> 2) * 64, j0 = (tile & 3) * 64;
    int wid = threadIdx.x >> 6, lane = threadIdx.x & 63;
    int wy = wid >> 1, wx = wid & 1;
    int iW = i0 + wy * 32, jW = j0 + wx * 32;
    int li = lane & 15, ko = (lane >> 4) * 8;

    f32x4 acc[2][2] = {};
    for (int r = 0; r < R_; r++) {
#pragma unroll
        for (int d0 = 0; d0 < 64; d0 += 32) {
            short8 aq[2], ak[2];
#pragma unroll
            for (int mi = 0; mi < 2; mi++) {
                size_t oq = ((size_t)((r * C_ + iW + mi * 16 + li) * N_ + n)) * E_ + h * 64 + d0 + ko;
                aq[mi] = *reinterpret_cast<const short8*>(q + oq);
                size_t ok = ((size_t)((r * C_ + jW + mi * 16 + li) * N_ + n)) * E_ + h * 64 + d0 + ko;
                ak[mi] = *reinterpret_cast<const short8*>(k + ok);
            }
#pragma unroll
            for (int mi = 0; mi < 2; mi++)
#pragma unroll
                for (int ni = 0; ni < 2; ni++)
                    acc[mi][ni] = __builtin_amdgcn_mfma_f32_16x16x32_bf16(aq[mi], ak[ni], acc[mi][ni], 0, 0, 0);
        }
    }
    const float scale = 0.02209708691207961f;  // (1/8) / sqrt(32)
#pragma unroll
    for (int mi = 0; mi < 2; mi++)
#pragma unroll
        for (int ni = 0; ni < 2; ni++)
#pragma unroll
            for (int r = 0; r < 4; r++) {
                int i = iW + mi * 16 + (lane >> 4) * 4 + r;
                int j = jW + ni * 16 + li;
                aw[((size_t)hn * C_ + i) * C_ + j] = acc[mi][ni][r] * scale;
            }
}

// ---------------- softmax over rows of length 256, in place ----------------
__global__ __launch_bounds__(256) void softmax256_kernel(float* __restrict__ aw) {
    int wid = threadIdx.x >> 6, lane = threadIdx.x & 63;
    size_t row = (size_t)blockIdx.x * 4 + wid;
    float* p = aw + row * 256;
    float4 v = reinterpret_cast<float4*>(p)[lane];
    float m = fmaxf(fmaxf(v.x, v.y), fmaxf(v.z, v.w));
#pragma unroll
    for (int off = 32; off >= 1; off >>= 1) m = fmaxf(m, __shfl_xor(m, off));
    float e0 = expf(v.x - m), e1 = expf(v.y - m), e2 = expf(v.z - m), e3 = expf(v.w - m);
    float s = e0 + e1 + e2 + e3;
#pragma unroll
    for (int off = 32; off >= 1; off >>= 1) s += __shfl_xor(s, off);
    float inv = 1.0f / s;
    float4 o; o.x = e0 * inv; o.y = e1 * inv; o.z = e2 * inv; o.w = e3 * inv;
    reinterpret_cast<float4*>(p)[lane] = o;
}

// ---------------- Row-attention AP·V: ctx[r,i,n,h,d] ----------------
__global__ __launch_bounds__(256) void row_ctx_kernel(const float* __restrict__ ap,
                                                      const u16* __restrict__ v,
                                                      u16* __restrict__ ctx) {
    int i0 = blockIdx.x * 64;     // 4 tiles
    int r = blockIdx.y;           // 32
    int hn = blockIdx.z;          // 48
    int h = hn >> 2, n = hn & 3;
    __shared__ u16 APs[64][40];
    __shared__ u16 Vts[64][40];   // Vt[d][j]
    int tid = threadIdx.x, wid = tid >> 6, lane = tid & 63;
    int wy = wid >> 1, wx = wid & 1;
    int li = lane & 15, ko = (lane >> 4) * 8;
    int ai = tid >> 2, aj = (tid & 3) * 8;   // AP staging: [64 i][32 j]
    int vj = tid >> 3, vd = (tid & 7) * 8;   // V staging: 32 j rows, 8 d each

    f32x4 acc[2][2] = {};
    for (int j0 = 0; j0 < C_; j0 += 32) {
        const float* aps = ap + ((size_t)hn * C_ + i0 + ai) * C_ + j0 + aj;
        float4 p0 = *reinterpret_cast<const float4*>(aps);
        float4 p1 = *reinterpret_cast<const float4*>(aps + 4);
        U8 t8;
        t8.u[0] = f2bf(p0.x); t8.u[1] = f2bf(p0.y); t8.u[2] = f2bf(p0.z); t8.u[3] = f2bf(p0.w);
        t8.u[4] = f2bf(p1.x); t8.u[5] = f2bf(p1.y); t8.u[6] = f2bf(p1.z); t8.u[7] = f2bf(p1.w);
        *reinterpret_cast<short8*>(&APs[ai][aj]) = t8.v;
        U8 vv;
        vv.v = *reinterpret_cast<const short8*>(
            v + ((size_t)((r * C_ + j0 + vj) * N_ + n)) * E_ + h * 64 + vd);
#pragma unroll
        for (int u = 0; u < 8; u++) Vts[vd + u][vj] = vv.u[u];
        __syncthreads();
        short8 af[2], vf[2];
        af[0] = *reinterpret_cast<const short8*>(&APs[wy * 32 + li][ko]);
        af[1] = *reinterpret_cast<const short8*>(&APs[wy * 32 + 16 + li][ko]);
        vf[0] = *reinterpret_cast<const short8*>(&Vts[wx * 32 + li][ko]);
        vf[1] = *reinterpret_cast<const short8*>(&Vts[wx * 32 + 16 + li][ko]);
#pragma unroll
        for (int mi = 0; mi < 2; mi++)
#pragma unroll
            for (int ni = 0; ni < 2; ni++)
                acc[mi][ni] = __builtin_amdgcn_mfma_f32_16x16x32_bf16(af[mi], vf[ni], acc[mi][ni], 0, 0, 0);
        __syncthreads();
    }
#pragma unroll
    for (int mi = 0; mi < 2; mi++)
#pragma unroll
        for (int ni = 0; ni < 2; ni++)
#pragma unroll
            for (int rr = 0; rr < 4; rr++) {
                int i = i0 + wy * 32 + mi * 16 + (lane >> 4) * 4 + rr;
                int d = wx * 32 + ni * 16 + li;
                ctx[((size_t)((r * C_ + i) * N_ + n)) * E_ + h * 64 + d] = f2bf(acc[mi][ni][rr]);
            }
}

// ---------------- Column attention, fully fused: one wave per (h,c,n) ----------------
__global__ __launch_bounds__(256) void col_attn_kernel(const u16* __restrict__ q,
                                                       const u16* __restrict__ k,
                                                       const u16* __restrict__ v,
                                                       u16* __restrict__ ctx) {
    __shared__ u16 P[4][32][40];
    int wid = threadIdx.x >> 6, lane = threadIdx.x & 63;
    int g = blockIdx.x * 4 + wid;        // 12288 = H * C * N
    int h = g >> 10;
    int cn = g & 1023;
    int c = cn >> 2, n = cn & 3;
    int li = lane & 15, ko = (lane >> 4) * 8;

    // ---- scores S[i][j] over rows i,j in [0,32), K = d = 64 ----
    f32x4 s[2][2] = {};
#pragma unroll
    for (int d0 = 0; d0 < 64; d0 += 32) {
        short8 aq[2], ak[2];
#pragma unroll
        for (int ia = 0; ia < 2; ia++) {
            size_t oq = ((size_t)(((ia * 16 + li) * C_ + c) * N_ + n)) * E_ + h * 64 + d0 + ko;
            aq[ia] = *reinterpret_cast<const short8*>(q + oq);
            ak[ia] = *reinterpret_cast<const short8*>(k + oq);  // same index formula for k
        }
#pragma unroll
        for (int ia = 0; ia < 2; ia++)
#pragma unroll
            for (int jb = 0; jb < 2; jb++)
                s[ia][jb] = __builtin_amdgcn_mfma_f32_16x16x32_bf16(aq[ia], ak[jb], s[ia][jb], 0, 0, 0);
    }
    // ---- softmax over j (32 values per row i) ----
#pragma unroll
    for (int ia = 0; ia < 2; ia++)
#pragma unroll
        for (int rr = 0; rr < 4; rr++) {
            float a0 = s[ia][0][rr] * 0.125f;
            float a1 = s[ia][1][rr] * 0.125f;
            float m = fmaxf(a0, a1);
#pragma unroll
            for (int off = 8; off >= 1; off >>= 1) m = fmaxf(m, __shfl_xor(m, off));
            float e0 = expf(a0 - m), e1 = expf(a1 - m);
            float ss = e0 + e1;
#pragma unroll
            for (int off = 8; off >= 1; off >>= 1) ss += __shfl_xor(ss, off);
            float inv = 1.0f / ss;
            s[ia][0][rr] = e0 * inv;
            s[ia][1][rr] = e1 * inv;
        }
    // ---- P -> LDS (C/D layout -> row-major) ----
#pragma unroll
    for (int ia = 0; ia < 2; ia++)
#pragma unroll
        for (int jb = 0; jb < 2; jb++)
#pragma unroll
            for (int rr = 0; rr < 4; rr++)
                P[wid][ia * 16 + (lane >> 4) * 4 + rr][jb * 16 + li] = f2bf(s[ia][jb][rr]);
    __syncthreads();
    // ---- PV: ctx[i][d] = sum_j P[i][j] * v[j][d] ----
    short8 pa[2];
    pa[0] = *reinterpret_cast<const short8*>(&P[wid][li][ko]);
    pa[1] = *reinterpret_cast<const short8*>(&P[wid][16 + li][ko]);
    f32x4 o[2][4] = {};
#pragma unroll
    for (int df = 0; df < 4; df++) {
        U8 vb;
#pragma unroll
        for (int jj = 0; jj < 8; jj++) {
            int j = (lane >> 4) * 8 + jj;
            vb.u[jj] = v[((size_t)((j * C_ + c) * N_ + n)) * E_ + h * 64 + df * 16 + li];
        }
#pragma unroll
        for (int ia = 0; ia < 2; ia++)
            o[ia][df] = __builtin_amdgcn_mfma_f32_16x16x32_bf16(pa[ia], vb.v, o[ia][df], 0, 0, 0);
    }
#pragma unroll
    for (int ia = 0; ia < 2; ia++)
#pragma unroll
        for (int df = 0; df < 4; df++)
#pragma unroll
            for (int rr = 0; rr < 4; rr++) {
                int i = ia * 16 + (lane >> 4) * 4 + rr;
                int d = df * 16 + li;
                ctx[((size_t)((i * C_ + c) * N_ + n)) * E_ + h * 64 + d] = f2bf(o[ia][df][rr]);
            }
}

// ---------------- launch ----------------
extern "C" void kernel_launch(void* const* d_in, const int* in_sizes, int n_in,
                              void* d_out, int out_size, void* d_ws, size_t ws_size,
                              hipStream_t stream) {
    const float* x     = (const float*)d_in[0];
    const float* ln_w  = (const float*)d_in[1];
    const float* ln_b  = (const float*)d_in[2];
    const float* row_w = (const float*)d_in[3];
    const float* row_b = (const float*)d_in[4];
    const float* col_w = (const float*)d_in[5];
    const float* col_b = (const float*)d_in[6];
    const float* fc1_w = (const float*)d_in[7];
    const float* fc1_b = (const float*)d_in[8];
    const float* fc2_w = (const float*)d_in[9];
    const float* fc2_b = (const float*)d_in[10];
    float* out = (float*)d_out;

    const size_t TE = (size_t)T_ * E_;
    u16* q_bf = (u16*)d_ws;
    u16* k_bf = q_bf + TE;
    u16* v_bf = k_bf + TE;
    u16* h_bf = v_bf + TE;                    // also ctx
    float* aw = (float*)(h_bf + TE);          // 48*256*256 fp32
    u16* wrow = (u16*)(aw + (size_t)48 * C_ * C_);
    u16* wcol = wrow + (size_t)4 * E_ * E_;
    u16* wfc1 = wcol + (size_t)4 * E_ * E_;
    u16* wfc2 = wfc1 + (size_t)F_ * E_;
    u16* hid = q_bf;                          // [T][1536] aliases q..k

    const int nW = 4 * E_ * E_;               // 2359296
    cvt_kernel<<<nW / 1024, 256, 0, stream>>>(row_w, wrow, nW);
    cvt_kernel<<<nW / 1024, 256, 0, stream>>>(col_w, wcol, nW);
    cvt_kernel<<<nW / 1024, 256, 0, stream>>>(fc1_w, wfc1, nW);
    cvt_kernel<<<nW / 1024, 256, 0, stream>>>(fc2_w, wfc2, nW);

    dim3 g768(E_ / 64, T_ / 64);     // (12, 512)
    dim3 g1536(F_ / 2 / 64, T_ / 64);// (24, 512)

    // ======== Row self-attention block ========
    ln_kernel<<<T_ / 4, 256, 0, stream>>>(x, ln_w, ln_b, h_bf);
    gemm_kernel<0, false><<<g768, 256, 0, stream>>>(h_bf, E_, wrow, E_, row_b, E_, q_bf, E_, nullptr, nullptr);
    gemm_kernel<0, false><<<g768, 256, 0, stream>>>(h_bf, E_, wrow + (size_t)E_ * E_, E_, row_b + E_, E_, k_bf, E_, nullptr, nullptr);
    gemm_kernel<0, false><<<g768, 256, 0, stream>>>(h_bf, E_, wrow + (size_t)2 * E_ * E_, E_, row_b + 2 * E_, E_, v_bf, E_, nullptr, nullptr);
    row_scores_kernel<<<dim3(16, 48), 256, 0, stream>>>(q_bf, k_bf, aw);
    softmax256_kernel<<<48 * C_ / 4, 256, 0, stream>>>(aw);
    row_ctx_kernel<<<dim3(4, 32, 48), 256, 0, stream>>>(aw, v_bf, h_bf);
    gemm_kernel<1, false><<<g768, 256, 0, stream>>>(h_bf, E_, wrow + (size_t)3 * E_ * E_, E_, row_b + 3 * E_, E_, nullptr, E_, out, x);

    // ======== Column self-attention block ========
    ln_kernel<<<T_ / 4, 256, 0, stream>>>(out, ln_w + E_, ln_b + E_, h_bf);
    gemm_kernel<0, false><<<g768, 256, 0, stream>>>(h_bf, E_, wcol, E_, col_b, E_, q_bf, E_, nullptr, nullptr);
    gemm_kernel<0, false><<<g768, 256, 0, stream>>>(h_bf, E_, wcol + (size_t)E_ * E_, E_, col_b + E_, E_, k_bf, E_, nullptr, nullptr);
    gemm_kernel<0, false><<<g768, 256, 0, stream>>>(h_bf, E_, wcol + (size_t)2 * E_ * E_, E_, col_b + 2 * E_, E_, v_bf, E_, nullptr, nullptr);
    col_attn_kernel<<<(H_ * C_ * N_) / 4, 256, 0, stream>>>(q_bf, k_bf, v_bf, h_bf);
    gemm_kernel<1, false><<<g768, 256, 0, stream>>>(h_bf, E_, wcol + (size_t)3 * E_ * E_, E_, col_b + 3 * E_, E_, nullptr, E_, out, out);

    // ======== FFN block (two K/N=1536 halves; hidden aliases q..k) ========
    ln_kernel<<<T_ / 4, 256, 0, stream>>>(out, ln_w + 2 * E_, ln_b + 2 * E_, h_bf);
    gemm_kernel<0, true><<<g1536, 256, 0, stream>>>(h_bf, E_, wfc1, E_, fc1_b, E_, hid, 1536, nullptr, nullptr);
    gemm_kernel<1, false><<<g768, 256, 0, stream>>>(hid, 1536, wfc2, F_, fc2_b, 1536, nullptr, E_, out, out);
    gemm_kernel<0, true><<<g1536, 256, 0, stream>>>(h_bf, E_, wfc1 + (size_t)1536 * E_, E_, fc1_b + 1536, E_, hid, 1536, nullptr, nullptr);
    gemm_kernel<1, false><<<g768, 256, 0, stream>>>(hid, 1536, wfc2 + 1536, F_, nullptr, 1536, nullptr, E_, out, out);
}

// Round 2
// 1416.026 us; speedup vs baseline: 1.3539x; 1.3539x over previous
//
#include <hip/hip_runtime.h>
#include <hip/hip_bf16.h>
#include <math.h>

typedef unsigned short u16;
typedef __attribute__((ext_vector_type(8))) short short8;
typedef __attribute__((ext_vector_type(4))) float f32x4;

#define E_ 768
#define H_ 12
#define D_ 64
#define C_ 256
#define R_ 32
#define N_ 4
#define F_ 3072
#define T_ 32768   // R_*C_*N_
#define TE_ ((size_t)T_ * E_)

union U8 { u16 u[8]; short8 v; };

__device__ __forceinline__ u16 f2bf(float f) {
    unsigned u = __builtin_bit_cast(unsigned, f);
    u = (u + 0x7FFFu + ((u >> 16) & 1u)) >> 16;
    return (u16)u;
}
__device__ __forceinline__ float bf2f(u16 h) {
    unsigned u = ((unsigned)h) << 16;
    return __builtin_bit_cast(float, u);
}

__device__ __forceinline__ void gload_lds16(const u16* g, u16* l) {
    __builtin_amdgcn_global_load_lds((const __attribute__((address_space(1))) void*)g,
                                     (__attribute__((address_space(3))) void*)l, 16, 0, 0);
}

// ---------------- fp32 -> bf16 weight convert ----------------
__global__ __launch_bounds__(256) void cvt_kernel(const float* __restrict__ src,
                                                  u16* __restrict__ dst, int n) {
    int i = (blockIdx.x * 256 + threadIdx.x) * 4;
    if (i >= n) return;
    float4 v = *reinterpret_cast<const float4*>(src + i);
    ushort4 o;
    o.x = f2bf(v.x); o.y = f2bf(v.y); o.z = f2bf(v.z); o.w = f2bf(v.w);
    *reinterpret_cast<ushort4*>(dst + i) = o;
}

// ---------------- LayerNorm: one wave per token (E=768) ----------------
__global__ __launch_bounds__(256) void ln_kernel(const float* __restrict__ x,
                                                 const float* __restrict__ w,
                                                 const float* __restrict__ b,
                                                 u16* __restrict__ out) {
    int wid = threadIdx.x >> 6, lane = threadIdx.x & 63;
    size_t t = (size_t)blockIdx.x * 4 + wid;
    const float* xp = x + t * E_;
    float4 v[3];
    float s1 = 0.f, s2 = 0.f;
#pragma unroll
    for (int c = 0; c < 3; c++) {
        v[c] = *reinterpret_cast<const float4*>(xp + c * 256 + lane * 4);
        s1 += v[c].x + v[c].y + v[c].z + v[c].w;
        s2 += v[c].x * v[c].x + v[c].y * v[c].y + v[c].z * v[c].z + v[c].w * v[c].w;
    }
#pragma unroll
    for (int off = 32; off >= 1; off >>= 1) {
        s1 += __shfl_xor(s1, off);
        s2 += __shfl_xor(s2, off);
    }
    float mu = s1 * (1.0f / E_);
    float var = s2 * (1.0f / E_) - mu * mu;
    float inv = rsqrtf(var + 1e-12f);
#pragma unroll
    for (int c = 0; c < 3; c++) {
        int e = c * 256 + lane * 4;
        float4 wv = *reinterpret_cast<const float4*>(w + e);
        float4 bv = *reinterpret_cast<const float4*>(b + e);
        ushort4 o;
        o.x = f2bf((v[c].x - mu) * inv * wv.x + bv.x);
        o.y = f2bf((v[c].y - mu) * inv * wv.y + bv.y);
        o.z = f2bf((v[c].z - mu) * inv * wv.z + bv.z);
        o.w = f2bf((v[c].w - mu) * inv * wv.w + bv.w);
        *reinterpret_cast<ushort4*>(out + t * E_ + e) = o;
    }
}

// ---------------- GEMM (m97 structure): 128x128 tile, BK=32, global_load_lds ----------------
// y[m,n] = A[m,:]·W[n,:] + bias
// MODE 0: store bf16 into dstB [m*ldd + n] (optional GELU)
// MODE 1: dstF[m*768+n] = resid[m*768+n] + acc  (fp32 residual add)
// MODE 2: qkv split: dstB + (n/768)*TE_ + m*768 + n%768  (bf16)
template<int MODE, bool GELU>
__global__ __launch_bounds__(256) void gemm128(
    const u16* __restrict__ A, int lda,
    const u16* __restrict__ W, int ldw,
    const float* __restrict__ bias, int K,
    u16* __restrict__ dstB, int ldd,
    float* __restrict__ dstF, const float* __restrict__ resid) {
    __shared__ u16 As[128 * 32];
    __shared__ u16 Ws[128 * 32];
    int tid = threadIdx.x;
    int m0 = blockIdx.y * 128, n0 = blockIdx.x * 128;
    int w = tid >> 6, lane = tid & 63;
    int wy = w >> 1, wx = w & 1;
    int li = lane & 15, ko = (lane >> 4) * 8;
    int srow = tid >> 2, scol = (tid & 3) * 8;

    const u16* ga = A + (size_t)(m0 + srow) * lda + scol;
    const u16* gw = W + (size_t)(n0 + srow) * ldw + scol;
    u16* lA0 = As + w * 512;
    u16* lA1 = As + 2048 + w * 512;
    u16* lW0 = Ws + w * 512;
    u16* lW1 = Ws + 2048 + w * 512;

    f32x4 acc[4][4] = {};
    for (int k0 = 0; k0 < K; k0 += 32) {
        gload_lds16(ga + k0, lA0);
        gload_lds16(ga + (size_t)64 * lda + k0, lA1);
        gload_lds16(gw + k0, lW0);
        gload_lds16(gw + (size_t)64 * ldw + k0, lW1);
        __syncthreads();
        short8 af[4], wf[4];
#pragma unroll
        for (int mi = 0; mi < 4; mi++)
            af[mi] = *reinterpret_cast<const short8*>(&As[(wy * 64 + mi * 16 + li) * 32 + ko]);
#pragma unroll
        for (int ni = 0; ni < 4; ni++)
            wf[ni] = *reinterpret_cast<const short8*>(&Ws[(wx * 64 + ni * 16 + li) * 32 + ko]);
#pragma unroll
        for (int mi = 0; mi < 4; mi++)
#pragma unroll
            for (int ni = 0; ni < 4; ni++)
                acc[mi][ni] = __builtin_amdgcn_mfma_f32_16x16x32_bf16(af[mi], wf[ni], acc[mi][ni], 0, 0, 0);
        __syncthreads();
    }
#pragma unroll
    for (int mi = 0; mi < 4; mi++)
#pragma unroll
        for (int ni = 0; ni < 4; ni++) {
            int n = n0 + wx * 64 + ni * 16 + li;
            float bn = bias ? bias[n] : 0.0f;
#pragma unroll
            for (int r = 0; r < 4; r++) {
                int m = m0 + wy * 64 + mi * 16 + (lane >> 4) * 4 + r;
                float vv = acc[mi][ni][r] + bn;
                if (GELU) vv = 0.5f * vv * (1.0f + erff(vv * 0.70710678118654752f));
                if (MODE == 0) {
                    dstB[(size_t)m * ldd + n] = f2bf(vv);
                } else if (MODE == 1) {
                    dstF[(size_t)m * E_ + n] = resid[(size_t)m * E_ + n] + vv;
                } else {
                    int third = (n >= 1536) ? 2 : ((n >= 768) ? 1 : 0);
                    dstB[(size_t)third * TE_ + (size_t)m * E_ + (n - third * 768)] = f2bf(vv);
                }
            }
        }
}

// ---------------- Row-attention scores: aw[h,n,i,j] = s * sum_{r,d} q·k ----------------
__global__ __launch_bounds__(256) void row_scores_kernel(const u16* __restrict__ q,
                                                         const u16* __restrict__ k,
                                                         float* __restrict__ aw) {
    int tile = blockIdx.x;            // 16: 4 i-tiles x 4 j-tiles
    int hn = blockIdx.y;              // 48
    int h = hn >> 2, n = hn & 3;
    int i0 = (tile >> 2) * 64, j0 = (tile & 3) * 64;
    int wid = threadIdx.x >> 6, lane = threadIdx.x & 63;
    int wy = wid >> 1, wx = wid & 1;
    int iW = i0 + wy * 32, jW = j0 + wx * 32;
    int li = lane & 15, ko = (lane >> 4) * 8;

    f32x4 acc[2][2] = {};
    for (int r = 0; r < R_; r++) {
#pragma unroll
        for (int d0 = 0; d0 < 64; d0 += 32) {
            short8 aq[2], ak[2];
#pragma unroll
            for (int mi = 0; mi < 2; mi++) {
                size_t oq = ((size_t)((r * C_ + iW + mi * 16 + li) * N_ + n)) * E_ + h * 64 + d0 + ko;
                aq[mi] = *reinterpret_cast<const short8*>(q + oq);
                size_t ok = ((size_t)((r * C_ + jW + mi * 16 + li) * N_ + n)) * E_ + h * 64 + d0 + ko;
                ak[mi] = *reinterpret_cast<const short8*>(k + ok);
            }
#pragma unroll
            for (int mi = 0; mi < 2; mi++)
#pragma unroll
                for (int ni = 0; ni < 2; ni++)
                    acc[mi][ni] = __builtin_amdgcn_mfma_f32_16x16x32_bf16(aq[mi], ak[ni], acc[mi][ni], 0, 0, 0);
        }
    }
    const float scale = 0.02209708691207961f;  // (1/8) / sqrt(32)
#pragma unroll
    for (int mi = 0; mi < 2; mi++)
#pragma unroll
        for (int ni = 0; ni < 2; ni++)
#pragma unroll
            for (int r = 0; r < 4; r++) {
                int i = iW + mi * 16 + (lane >> 4) * 4 + r;
                int j = jW + ni * 16 + li;
                aw[((size_t)hn * C_ + i) * C_ + j] = acc[mi][ni][r] * scale;
            }
}

// ---------------- softmax over rows of length 256, in place ----------------
__global__ __launch_bounds__(256) void softmax256_kernel(float* __restrict__ aw) {
    int wid = threadIdx.x >> 6, lane = threadIdx.x & 63;
    size_t row = (size_t)blockIdx.x * 4 + wid;
    float* p = aw + row * 256;
    float4 v = reinterpret_cast<float4*>(p)[lane];
    float m = fmaxf(fmaxf(v.x, v.y), fmaxf(v.z, v.w));
#pragma unroll
    for (int off = 32; off >= 1; off >>= 1) m = fmaxf(m, __shfl_xor(m, off));
    float e0 = expf(v.x - m), e1 = expf(v.y - m), e2 = expf(v.z - m), e3 = expf(v.w - m);
    float s = e0 + e1 + e2 + e3;
#pragma unroll
    for (int off = 32; off >= 1; off >>= 1) s += __shfl_xor(s, off);
    float inv = 1.0f / s;
    float4 o; o.x = e0 * inv; o.y = e1 * inv; o.z = e2 * inv; o.w = e3 * inv;
    reinterpret_cast<float4*>(p)[lane] = o;
}

// ---------------- Row-attention AP·V: ctx[r,i,n,h,d] ----------------
__global__ __launch_bounds__(256) void row_ctx_kernel(const float* __restrict__ ap,
                                                      const u16* __restrict__ v,
                                                      u16* __restrict__ ctx) {
    int i0 = blockIdx.x * 64;     // 4 tiles
    int r = blockIdx.y;           // 32
    int hn = blockIdx.z;          // 48
    int h = hn >> 2, n = hn & 3;
    __shared__ u16 APs[64][40];
    __shared__ u16 Vts[64][40];   // Vt[d][j]
    int tid = threadIdx.x, wid = tid >> 6, lane = tid & 63;
    int wy = wid >> 1, wx = wid & 1;
    int li = lane & 15, ko = (lane >> 4) * 8;
    int ai = tid >> 2, aj = (tid & 3) * 8;   // AP staging: [64 i][32 j]
    int vj = tid >> 3, vd = (tid & 7) * 8;   // V staging: 32 j rows, 8 d each

    f32x4 acc[2][2] = {};
    for (int j0 = 0; j0 < C_; j0 += 32) {
        const float* aps = ap + ((size_t)hn * C_ + i0 + ai) * C_ + j0 + aj;
        float4 p0 = *reinterpret_cast<const float4*>(aps);
        float4 p1 = *reinterpret_cast<const float4*>(aps + 4);
        U8 t8;
        t8.u[0] = f2bf(p0.x); t8.u[1] = f2bf(p0.y); t8.u[2] = f2bf(p0.z); t8.u[3] = f2bf(p0.w);
        t8.u[4] = f2bf(p1.x); t8.u[5] = f2bf(p1.y); t8.u[6] = f2bf(p1.z); t8.u[7] = f2bf(p1.w);
        *reinterpret_cast<short8*>(&APs[ai][aj]) = t8.v;
        U8 vv;
        vv.v = *reinterpret_cast<const short8*>(
            v + ((size_t)((r * C_ + j0 + vj) * N_ + n)) * E_ + h * 64 + vd);
#pragma unroll
        for (int u = 0; u < 8; u++) Vts[vd + u][vj] = vv.u[u];
        __syncthreads();
        short8 af[2], vf[2];
        af[0] = *reinterpret_cast<const short8*>(&APs[wy * 32 + li][ko]);
        af[1] = *reinterpret_cast<const short8*>(&APs[wy * 32 + 16 + li][ko]);
        vf[0] = *reinterpret_cast<const short8*>(&Vts[wx * 32 + li][ko]);
        vf[1] = *reinterpret_cast<const short8*>(&Vts[wx * 32 + 16 + li][ko]);
#pragma unroll
        for (int mi = 0; mi < 2; mi++)
#pragma unroll
            for (int ni = 0; ni < 2; ni++)
                acc[mi][ni] = __builtin_amdgcn_mfma_f32_16x16x32_bf16(af[mi], vf[ni], acc[mi][ni], 0, 0, 0);
        __syncthreads();
    }
#pragma unroll
    for (int mi = 0; mi < 2; mi++)
#pragma unroll
        for (int ni = 0; ni < 2; ni++)
#pragma unroll
            for (int rr = 0; rr < 4; rr++) {
                int i = i0 + wy * 32 + mi * 16 + (lane >> 4) * 4 + rr;
                int d = wx * 32 + ni * 16 + li;
                ctx[((size_t)((r * C_ + i) * N_ + n)) * E_ + h * 64 + d] = f2bf(acc[mi][ni][rr]);
            }
}

// ---------------- Column attention, fully fused: one wave per (h,c,n) ----------------
__global__ __launch_bounds__(256) void col_attn_kernel(const u16* __restrict__ q,
                                                       const u16* __restrict__ k,
                                                       const u16* __restrict__ v,
                                                       u16* __restrict__ ctx) {
    __shared__ u16 P[4][32][40];
    int wid = threadIdx.x >> 6, lane = threadIdx.x & 63;
    int g = blockIdx.x * 4 + wid;        // 12288 = H * C * N
    int h = g >> 10;
    int cn = g & 1023;
    int c = cn >> 2, n = cn & 3;
    int li = lane & 15, ko = (lane >> 4) * 8;

    // ---- scores S[i][j] over rows i,j in [0,32), K = d = 64 ----
    f32x4 s[2][2] = {};
#pragma unroll
    for (int d0 = 0; d0 < 64; d0 += 32) {
        short8 aq[2], ak[2];
#pragma unroll
        for (int ia = 0; ia < 2; ia++) {
            size_t oq = ((size_t)(((ia * 16 + li) * C_ + c) * N_ + n)) * E_ + h * 64 + d0 + ko;
            aq[ia] = *reinterpret_cast<const short8*>(q + oq);
            ak[ia] = *reinterpret_cast<const short8*>(k + oq);  // same index formula for k
        }
#pragma unroll
        for (int ia = 0; ia < 2; ia++)
#pragma unroll
            for (int jb = 0; jb < 2; jb++)
                s[ia][jb] = __builtin_amdgcn_mfma_f32_16x16x32_bf16(aq[ia], ak[jb], s[ia][jb], 0, 0, 0);
    }
    // ---- softmax over j (32 values per row i) ----
#pragma unroll
    for (int ia = 0; ia < 2; ia++)
#pragma unroll
        for (int rr = 0; rr < 4; rr++) {
            float a0 = s[ia][0][rr] * 0.125f;
            float a1 = s[ia][1][rr] * 0.125f;
            float m = fmaxf(a0, a1);
#pragma unroll
            for (int off = 8; off >= 1; off >>= 1) m = fmaxf(m, __shfl_xor(m, off));
            float e0 = expf(a0 - m), e1 = expf(a1 - m);
            float ss = e0 + e1;
#pragma unroll
            for (int off = 8; off >= 1; off >>= 1) ss += __shfl_xor(ss, off);
            float inv = 1.0f / ss;
            s[ia][0][rr] = e0 * inv;
            s[ia][1][rr] = e1 * inv;
        }
    // ---- P -> LDS (C/D layout -> row-major) ----
#pragma unroll
    for (int ia = 0; ia < 2; ia++)
#pragma unroll
        for (int jb = 0; jb < 2; jb++)
#pragma unroll
            for (int rr = 0; rr < 4; rr++)
                P[wid][ia * 16 + (lane >> 4) * 4 + rr][jb * 16 + li] = f2bf(s[ia][jb][rr]);
    __syncthreads();
    // ---- PV: ctx[i][d] = sum_j P[i][j] * v[j][d] ----
    short8 pa[2];
    pa[0] = *reinterpret_cast<const short8*>(&P[wid][li][ko]);
    pa[1] = *reinterpret_cast<const short8*>(&P[wid][16 + li][ko]);
    f32x4 o[2][4] = {};
#pragma unroll
    for (int df = 0; df < 4; df++) {
        U8 vb;
#pragma unroll
        for (int jj = 0; jj < 8; jj++) {
            int j = (lane >> 4) * 8 + jj;
            vb.u[jj] = v[((size_t)((j * C_ + c) * N_ + n)) * E_ + h * 64 + df * 16 + li];
        }
#pragma unroll
        for (int ia = 0; ia < 2; ia++)
            o[ia][df] = __builtin_amdgcn_mfma_f32_16x16x32_bf16(pa[ia], vb.v, o[ia][df], 0, 0, 0);
    }
#pragma unroll
    for (int ia = 0; ia < 2; ia++)
#pragma unroll
        for (int df = 0; df < 4; df++)
#pragma unroll
            for (int rr = 0; rr < 4; rr++) {
                int i = ia * 16 + (lane >> 4) * 4 + rr;
                int d = df * 16 + li;
                ctx[((size_t)((i * C_ + c) * N_ + n)) * E_ + h * 64 + d] = f2bf(o[ia][df][rr]);
            }
}

// ---------------- launch ----------------
extern "C" void kernel_launch(void* const* d_in, const int* in_sizes, int n_in,
                              void* d_out, int out_size, void* d_ws, size_t ws_size,
                              hipStream_t stream) {
    const float* x     = (const float*)d_in[0];
    const float* ln_w  = (const float*)d_in[1];
    const float* ln_b  = (const float*)d_in[2];
    const float* row_w = (const float*)d_in[3];
    const float* row_b = (const float*)d_in[4];
    const float* col_w = (const float*)d_in[5];
    const float* col_b = (const float*)d_in[6];
    const float* fc1_w = (const float*)d_in[7];
    const float* fc1_b = (const float*)d_in[8];
    const float* fc2_w = (const float*)d_in[9];
    const float* fc2_b = (const float*)d_in[10];
    float* out = (float*)d_out;

    u16* q_bf = (u16*)d_ws;
    u16* k_bf = q_bf + TE_;
    u16* v_bf = k_bf + TE_;
    u16* h_bf = v_bf + TE_;                   // also ctx
    float* aw = (float*)(h_bf + TE_);         // 48*256*256 fp32
    u16* wrow = (u16*)(aw + (size_t)48 * C_ * C_);
    u16* wcol = wrow + (size_t)4 * E_ * E_;
    u16* wfc1 = wcol + (size_t)4 * E_ * E_;
    u16* wfc2 = wfc1 + (size_t)F_ * E_;
    u16* hid = q_bf;                          // [T][1536] aliases q..k

    const int nW = 4 * E_ * E_;               // 2359296
    cvt_kernel<<<nW / 1024, 256, 0, stream>>>(row_w, wrow, nW);
    cvt_kernel<<<nW / 1024, 256, 0, stream>>>(col_w, wcol, nW);
    cvt_kernel<<<nW / 1024, 256, 0, stream>>>(fc1_w, wfc1, nW);
    cvt_kernel<<<nW / 1024, 256, 0, stream>>>(fc2_w, wfc2, nW);

    dim3 gQKV(18, 256);              // N=2304 fused qkv
    dim3 gOUT(6, 256);               // N=768
    dim3 gFC1(12, 256);              // N=1536 (one half)

    // ======== Row self-attention block ========
    ln_kernel<<<T_ / 4, 256, 0, stream>>>(x, ln_w, ln_b, h_bf);
    gemm128<2, false><<<gQKV, 256, 0, stream>>>(h_bf, E_, wrow, E_, row_b, E_, q_bf, E_, nullptr, nullptr);
    row_scores_kernel<<<dim3(16, 48), 256, 0, stream>>>(q_bf, k_bf, aw);
    softmax256_kernel<<<48 * C_ / 4, 256, 0, stream>>>(aw);
    row_ctx_kernel<<<dim3(4, 32, 48), 256, 0, stream>>>(aw, v_bf, h_bf);
    gemm128<1, false><<<gOUT, 256, 0, stream>>>(h_bf, E_, wrow + (size_t)3 * E_ * E_, E_, row_b + 3 * E_, E_, nullptr, E_, out, x);

    // ======== Column self-attention block ========
    ln_kernel<<<T_ / 4, 256, 0, stream>>>(out, ln_w + E_, ln_b + E_, h_bf);
    gemm128<2, false><<<gQKV, 256, 0, stream>>>(h_bf, E_, wcol, E_, col_b, E_, q_bf, E_, nullptr, nullptr);
    col_attn_kernel<<<(H_ * C_ * N_) / 4, 256, 0, stream>>>(q_bf, k_bf, v_bf, h_bf);
    gemm128<1, false><<<gOUT, 256, 0, stream>>>(h_bf, E_, wcol + (size_t)3 * E_ * E_, E_, col_b + 3 * E_, E_, nullptr, E_, out, out);

    // ======== FFN block (two K/N=1536 halves; hidden aliases q..k) ========
    ln_kernel<<<T_ / 4, 256, 0, stream>>>(out, ln_w + 2 * E_, ln_b + 2 * E_, h_bf);
    gemm128<0, true><<<gFC1, 256, 0, stream>>>(h_bf, E_, wfc1, E_, fc1_b, E_, hid, 1536, nullptr, nullptr);
    gemm128<1, false><<<gOUT, 256, 0, stream>>>(hid, 1536, wfc2, F_, fc2_b, 1536, nullptr, E_, out, out);
    gemm128<0, true><<<gFC1, 256, 0, stream>>>(h_bf, E_, wfc1 + (size_t)1536 * E_, E_, fc1_b + 1536, E_, hid, 1536, nullptr, nullptr);
    gemm128<1, false><<<gOUT, 256, 0, stream>>>(hid, 1536, wfc2 + 1536, F_, nullptr, 1536, nullptr, E_, out, out);
}

// Round 3
// 1292.644 us; speedup vs baseline: 1.4831x; 1.0954x over previous
//
#include <hip/hip_runtime.h>
#include <hip/hip_bf16.h>
#include <math.h>

typedef unsigned short u16;
typedef __attribute__((ext_vector_type(8))) short short8;
typedef __attribute__((ext_vector_type(4))) float f32x4;

#define E_ 768
#define H_ 12
#define D_ 64
#define C_ 256
#define R_ 32
#define N_ 4
#define F_ 3072
#define T_ 32768   // R_*C_*N_
#define TE_ ((size_t)T_ * E_)

union U8 { u16 u[8]; short8 v; };

__device__ __forceinline__ u16 f2bf(float f) {
    unsigned u = __builtin_bit_cast(unsigned, f);
    u = (u + 0x7FFFu + ((u >> 16) & 1u)) >> 16;
    return (u16)u;
}
__device__ __forceinline__ float bf2f(u16 h) {
    unsigned u = ((unsigned)h) << 16;
    return __builtin_bit_cast(float, u);
}

__device__ __forceinline__ void gload_lds16(const u16* g, u16* l) {
    __builtin_amdgcn_global_load_lds((const __attribute__((address_space(1))) void*)g,
                                     (__attribute__((address_space(3))) void*)l, 16, 0, 0);
}

// ---------------- fp32 -> bf16 weight convert ----------------
__global__ __launch_bounds__(256) void cvt_kernel(const float* __restrict__ src,
                                                  u16* __restrict__ dst, int n) {
    int i = (blockIdx.x * 256 + threadIdx.x) * 4;
    if (i >= n) return;
    float4 v = *reinterpret_cast<const float4*>(src + i);
    ushort4 o;
    o.x = f2bf(v.x); o.y = f2bf(v.y); o.z = f2bf(v.z); o.w = f2bf(v.w);
    *reinterpret_cast<ushort4*>(dst + i) = o;
}

// ---------------- LayerNorm: one wave per token (E=768) ----------------
__global__ __launch_bounds__(256) void ln_kernel(const float* __restrict__ x,
                                                 const float* __restrict__ w,
                                                 const float* __restrict__ b,
                                                 u16* __restrict__ out) {
    int wid = threadIdx.x >> 6, lane = threadIdx.x & 63;
    size_t t = (size_t)blockIdx.x * 4 + wid;
    const float* xp = x + t * E_;
    float4 v[3];
    float s1 = 0.f, s2 = 0.f;
#pragma unroll
    for (int c = 0; c < 3; c++) {
        v[c] = *reinterpret_cast<const float4*>(xp + c * 256 + lane * 4);
        s1 += v[c].x + v[c].y + v[c].z + v[c].w;
        s2 += v[c].x * v[c].x + v[c].y * v[c].y + v[c].z * v[c].z + v[c].w * v[c].w;
    }
#pragma unroll
    for (int off = 32; off >= 1; off >>= 1) {
        s1 += __shfl_xor(s1, off);
        s2 += __shfl_xor(s2, off);
    }
    float mu = s1 * (1.0f / E_);
    float var = s2 * (1.0f / E_) - mu * mu;
    float inv = rsqrtf(var + 1e-12f);
#pragma unroll
    for (int c = 0; c < 3; c++) {
        int e = c * 256 + lane * 4;
        float4 wv = *reinterpret_cast<const float4*>(w + e);
        float4 bv = *reinterpret_cast<const float4*>(b + e);
        ushort4 o;
        o.x = f2bf((v[c].x - mu) * inv * wv.x + bv.x);
        o.y = f2bf((v[c].y - mu) * inv * wv.y + bv.y);
        o.z = f2bf((v[c].z - mu) * inv * wv.z + bv.z);
        o.w = f2bf((v[c].w - mu) * inv * wv.w + bv.w);
        *reinterpret_cast<ushort4*>(out + t * E_ + e) = o;
    }
}

// ================= 256x256 pipelined GEMM (T1+T2+T3+T4+T5) =================
// y[m,n] = A[m,:]·W[n,:] + bias ;  BK=32, 4-deep LDS pipeline, counted vmcnt.
// LDS layout: A bufs: 4 x 16KB @ byte 0 ; B bufs: 4 x 16KB @ byte 65536.
// Tile rows stored as 128B row-pairs, bytes XOR-swizzled by ((rowpair&7)<<4).
// MODE 0: store bf16 dstB[m*ldd+n] (opt GELU). MODE 1: dstF = resid + acc (fp32).
// MODE 2: qkv split: dstB + (n/768)*TE_ + m*768 + n%768.
template<int MODE, bool GELU, int NT>
__global__ __launch_bounds__(512, 1) void gemm256(
    const u16* __restrict__ A, int lda,
    const u16* __restrict__ W, int ldw,
    const float* __restrict__ bias,
    u16* __restrict__ dstB, int ldd,
    float* __restrict__ dstF, const float* __restrict__ resid,
    int nt_n) {
    static_assert(NT >= 4, "pipeline needs >=4 K-tiles");
    __shared__ u16 lds[65536];   // 128 KB
    const int tid = threadIdx.x;
    const int w = tid >> 6, lane = tid & 63;
    const int wm = w >> 2, wn = w & 3;
    const int li = lane & 15, hi = lane >> 4;

    // ---- T1: XCD-contiguous swizzle + supergroups of 8 m-tiles (n-outer) ----
    int nwg = gridDim.x;
    int cpx = nwg >> 3;                       // nwg % 8 == 0 for all our grids
    int lbid = (blockIdx.x & 7) * cpx + (blockIdx.x >> 3);
    int sgsz = nt_n << 3;
    int sg = lbid / sgsz, rem = lbid - sg * sgsz;
    int nt = rem >> 3, mt = (sg << 3) + (rem & 7);
    int m0 = mt << 8, n0 = nt << 8;

    // ---- staging source mapping (inverse of LDS read swizzle) ----
    int t7 = ((tid & 7) * 16) ^ (((tid >> 3) & 7) << 4);
    int rloc = ((tid >> 3) << 1) | (t7 >> 6);   // local row in a 128-row half
    int cel = (t7 & 63) >> 1;                   // k element offset (0..31)
    const u16* gA0 = A + (size_t)(m0 + rloc) * lda + cel;
    const u16* gA1 = A + (size_t)(m0 + 128 + rloc) * lda + cel;
    const u16* gW0 = W + (size_t)(n0 + rloc) * ldw + cel;
    const u16* gW1 = W + (size_t)(n0 + 128 + rloc) * ldw + cel;
    const int dA0 = w * 512;            // u16 idx; +buf*8192, chunk1 +4096
    const int dB0 = 32768 + w * 512;

    // ---- frag read base addresses (bytes, swizzled) ----
    const int colx = (((lane & 1) * 64) | (hi * 16)) ^ (((li >> 1) & 7) << 4);
    const int aAb = (wm * 64 + (li >> 1)) * 128 + colx;           // +buf*16384 +mf*1024
    const int aBb = 65536 + (wn * 32 + (li >> 1)) * 128 + colx;   // +buf*16384 +nf*1024

    f32x4 acc[8][4] = {};

#define STAGE_(kt) {                                                   \
        int koff = (kt) * 32; int b_ = (kt) & 3;                       \
        gload_lds16(gA0 + koff, lds + b_ * 8192 + dA0);                \
        gload_lds16(gA1 + koff, lds + b_ * 8192 + 4096 + dA0);         \
        gload_lds16(gW0 + koff, lds + b_ * 8192 + dB0);                \
        gload_lds16(gW1 + koff, lds + b_ * 8192 + 4096 + dB0);        }

#define BODY_(t, WAITS, DO_STAGE) {                                    \
        asm volatile(WAITS ::: "memory");                              \
        int b_ = (t) & 3;                                              \
        const u16* pa_ = lds + ((b_ * 16384 + aAb) >> 1);              \
        const u16* pb_ = lds + ((b_ * 16384 + aBb) >> 1);              \
        short8 af[8], bfr[4];                                          \
        _Pragma("unroll") for (int mf = 0; mf < 8; mf++)               \
            af[mf] = *reinterpret_cast<const short8*>(pa_ + mf * 512); \
        _Pragma("unroll") for (int nf = 0; nf < 4; nf++)               \
            bfr[nf] = *reinterpret_cast<const short8*>(pb_ + nf * 512);\
        if (DO_STAGE) STAGE_((t) + 3);                                 \
        __builtin_amdgcn_s_setprio(1);                                 \
        _Pragma("unroll") for (int mf = 0; mf < 8; mf++)               \
            _Pragma("unroll") for (int nf = 0; nf < 4; nf++)           \
                acc[mf][nf] = __builtin_amdgcn_mfma_f32_16x16x32_bf16( \
                    af[mf], bfr[nf], acc[mf][nf], 0, 0, 0);            \
        __builtin_amdgcn_s_setprio(0);                                }

    STAGE_(0); STAGE_(1); STAGE_(2);
#pragma unroll 1
    for (int t = 0; t < NT - 3; ++t) {
        BODY_(t, "s_waitcnt vmcnt(8)\ns_barrier", true);
    }
    BODY_(NT - 3, "s_waitcnt vmcnt(8)\ns_barrier", false);
    BODY_(NT - 2, "s_waitcnt vmcnt(4)\ns_barrier", false);
    BODY_(NT - 1, "s_waitcnt vmcnt(0)\ns_barrier", false);
#undef BODY_
#undef STAGE_

    // ---- epilogue ----
#pragma unroll
    for (int mf = 0; mf < 8; mf++)
#pragma unroll
        for (int nf = 0; nf < 4; nf++) {
            int n = n0 + wn * 64 + nf * 16 + li;
            float bn = bias ? bias[n] : 0.0f;
#pragma unroll
            for (int r = 0; r < 4; r++) {
                int m = m0 + wm * 128 + mf * 16 + hi * 4 + r;
                float vv = acc[mf][nf][r] + bn;
                if (GELU) vv = 0.5f * vv * (1.0f + erff(vv * 0.70710678118654752f));
                if (MODE == 0) {
                    dstB[(size_t)m * ldd + n] = f2bf(vv);
                } else if (MODE == 1) {
                    dstF[(size_t)m * E_ + n] = resid[(size_t)m * E_ + n] + vv;
                } else {
                    int third = (n >= 1536) ? 2 : ((n >= 768) ? 1 : 0);
                    dstB[(size_t)third * TE_ + (size_t)m * E_ + (n - third * 768)] = f2bf(vv);
                }
            }
        }
}

// ---------------- Row-attention scores: aw[h,n,i,j] = s * sum_{r,d} q·k ----------------
__global__ __launch_bounds__(256) void row_scores_kernel(const u16* __restrict__ q,
                                                         const u16* __restrict__ k,
                                                         float* __restrict__ aw) {
    int tile = blockIdx.x;            // 16: 4 i-tiles x 4 j-tiles
    int hn = blockIdx.y;              // 48
    int h = hn >> 2, n = hn & 3;
    int i0 = (tile >> 2) * 64, j0 = (tile & 3) * 64;
    int wid = threadIdx.x >> 6, lane = threadIdx.x & 63;
    int wy = wid >> 1, wx = wid & 1;
    int iW = i0 + wy * 32, jW = j0 + wx * 32;
    int li = lane & 15, ko = (lane >> 4) * 8;

    f32x4 acc[2][2] = {};
    for (int r = 0; r < R_; r++) {
#pragma unroll
        for (int d0 = 0; d0 < 64; d0 += 32) {
            short8 aq[2], ak[2];
#pragma unroll
            for (int mi = 0; mi < 2; mi++) {
                size_t oq = ((size_t)((r * C_ + iW + mi * 16 + li) * N_ + n)) * E_ + h * 64 + d0 + ko;
                aq[mi] = *reinterpret_cast<const short8*>(q + oq);
                size_t ok = ((size_t)((r * C_ + jW + mi * 16 + li) * N_ + n)) * E_ + h * 64 + d0 + ko;
                ak[mi] = *reinterpret_cast<const short8*>(k + ok);
            }
#pragma unroll
            for (int mi = 0; mi < 2; mi++)
#pragma unroll
                for (int ni = 0; ni < 2; ni++)
                    acc[mi][ni] = __builtin_amdgcn_mfma_f32_16x16x32_bf16(aq[mi], ak[ni], acc[mi][ni], 0, 0, 0);
        }
    }
    const float scale = 0.02209708691207961f;  // (1/8) / sqrt(32)
#pragma unroll
    for (int mi = 0; mi < 2; mi++)
#pragma unroll
        for (int ni = 0; ni < 2; ni++)
#pragma unroll
            for (int r = 0; r < 4; r++) {
                int i = iW + mi * 16 + (lane >> 4) * 4 + r;
                int j = jW + ni * 16 + li;
                aw[((size_t)hn * C_ + i) * C_ + j] = acc[mi][ni][r] * scale;
            }
}

// ---------------- softmax over rows of length 256, in place ----------------
__global__ __launch_bounds__(256) void softmax256_kernel(float* __restrict__ aw) {
    int wid = threadIdx.x >> 6, lane = threadIdx.x & 63;
    size_t row = (size_t)blockIdx.x * 4 + wid;
    float* p = aw + row * 256;
    float4 v = reinterpret_cast<float4*>(p)[lane];
    float m = fmaxf(fmaxf(v.x, v.y), fmaxf(v.z, v.w));
#pragma unroll
    for (int off = 32; off >= 1; off >>= 1) m = fmaxf(m, __shfl_xor(m, off));
    float e0 = expf(v.x - m), e1 = expf(v.y - m), e2 = expf(v.z - m), e3 = expf(v.w - m);
    float s = e0 + e1 + e2 + e3;
#pragma unroll
    for (int off = 32; off >= 1; off >>= 1) s += __shfl_xor(s, off);
    float inv = 1.0f / s;
    float4 o; o.x = e0 * inv; o.y = e1 * inv; o.z = e2 * inv; o.w = e3 * inv;
    reinterpret_cast<float4*>(p)[lane] = o;
}

// ---------------- Row-attention AP·V: ctx[r,i,n,h,d] ----------------
__global__ __launch_bounds__(256) void row_ctx_kernel(const float* __restrict__ ap,
                                                      const u16* __restrict__ v,
                                                      u16* __restrict__ ctx) {
    int i0 = blockIdx.x * 64;     // 4 tiles
    int r = blockIdx.y;           // 32
    int hn = blockIdx.z;          // 48
    int h = hn >> 2, n = hn & 3;
    __shared__ u16 APs[64][40];
    __shared__ u16 Vts[64][40];   // Vt[d][j]
    int tid = threadIdx.x, wid = tid >> 6, lane = tid & 63;
    int wy = wid >> 1, wx = wid & 1;
    int li = lane & 15, ko = (lane >> 4) * 8;
    int ai = tid >> 2, aj = (tid & 3) * 8;   // AP staging: [64 i][32 j]
    int vj = tid >> 3, vd = (tid & 7) * 8;   // V staging: 32 j rows, 8 d each

    f32x4 acc[2][2] = {};
    for (int j0 = 0; j0 < C_; j0 += 32) {
        const float* aps = ap + ((size_t)hn * C_ + i0 + ai) * C_ + j0 + aj;
        float4 p0 = *reinterpret_cast<const float4*>(aps);
        float4 p1 = *reinterpret_cast<const float4*>(aps + 4);
        U8 t8;
        t8.u[0] = f2bf(p0.x); t8.u[1] = f2bf(p0.y); t8.u[2] = f2bf(p0.z); t8.u[3] = f2bf(p0.w);
        t8.u[4] = f2bf(p1.x); t8.u[5] = f2bf(p1.y); t8.u[6] = f2bf(p1.z); t8.u[7] = f2bf(p1.w);
        *reinterpret_cast<short8*>(&APs[ai][aj]) = t8.v;
        U8 vv;
        vv.v = *reinterpret_cast<const short8*>(
            v + ((size_t)((r * C_ + j0 + vj) * N_ + n)) * E_ + h * 64 + vd);
#pragma unroll
        for (int u = 0; u < 8; u++) Vts[vd + u][vj] = vv.u[u];
        __syncthreads();
        short8 af[2], vf[2];
        af[0] = *reinterpret_cast<const short8*>(&APs[wy * 32 + li][ko]);
        af[1] = *reinterpret_cast<const short8*>(&APs[wy * 32 + 16 + li][ko]);
        vf[0] = *reinterpret_cast<const short8*>(&Vts[wx * 32 + li][ko]);
        vf[1] = *reinterpret_cast<const short8*>(&Vts[wx * 32 + 16 + li][ko]);
#pragma unroll
        for (int mi = 0; mi < 2; mi++)
#pragma unroll
            for (int ni = 0; ni < 2; ni++)
                acc[mi][ni] = __builtin_amdgcn_mfma_f32_16x16x32_bf16(af[mi], vf[ni], acc[mi][ni], 0, 0, 0);
        __syncthreads();
    }
#pragma unroll
    for (int mi = 0; mi < 2; mi++)
#pragma unroll
        for (int ni = 0; ni < 2; ni++)
#pragma unroll
            for (int rr = 0; rr < 4; rr++) {
                int i = i0 + wy * 32 + mi * 16 + (lane >> 4) * 4 + rr;
                int d = wx * 32 + ni * 16 + li;
                ctx[((size_t)((r * C_ + i) * N_ + n)) * E_ + h * 64 + d] = f2bf(acc[mi][ni][rr]);
            }
}

// ---------------- Column attention, fully fused: one wave per (h,c,n) ----------------
__global__ __launch_bounds__(256) void col_attn_kernel(const u16* __restrict__ q,
                                                       const u16* __restrict__ k,
                                                       const u16* __restrict__ v,
                                                       u16* __restrict__ ctx) {
    __shared__ u16 P[4][32][40];
    int wid = threadIdx.x >> 6, lane = threadIdx.x & 63;
    int g = blockIdx.x * 4 + wid;        // 12288 = H * C * N
    int h = g >> 10;
    int cn = g & 1023;
    int c = cn >> 2, n = cn & 3;
    int li = lane & 15, ko = (lane >> 4) * 8;

    // ---- scores S[i][j] over rows i,j in [0,32), K = d = 64 ----
    f32x4 s[2][2] = {};
#pragma unroll
    for (int d0 = 0; d0 < 64; d0 += 32) {
        short8 aq[2], ak[2];
#pragma unroll
        for (int ia = 0; ia < 2; ia++) {
            size_t oq = ((size_t)(((ia * 16 + li) * C_ + c) * N_ + n)) * E_ + h * 64 + d0 + ko;
            aq[ia] = *reinterpret_cast<const short8*>(q + oq);
            ak[ia] = *reinterpret_cast<const short8*>(k + oq);  // same index formula for k
        }
#pragma unroll
        for (int ia = 0; ia < 2; ia++)
#pragma unroll
            for (int jb = 0; jb < 2; jb++)
                s[ia][jb] = __builtin_amdgcn_mfma_f32_16x16x32_bf16(aq[ia], ak[jb], s[ia][jb], 0, 0, 0);
    }
    // ---- softmax over j (32 values per row i) ----
#pragma unroll
    for (int ia = 0; ia < 2; ia++)
#pragma unroll
        for (int rr = 0; rr < 4; rr++) {
            float a0 = s[ia][0][rr] * 0.125f;
            float a1 = s[ia][1][rr] * 0.125f;
            float m = fmaxf(a0, a1);
#pragma unroll
            for (int off = 8; off >= 1; off >>= 1) m = fmaxf(m, __shfl_xor(m, off));
            float e0 = expf(a0 - m), e1 = expf(a1 - m);
            float ss = e0 + e1;
#pragma unroll
            for (int off = 8; off >= 1; off >>= 1) ss += __shfl_xor(ss, off);
            float inv = 1.0f / ss;
            s[ia][0][rr] = e0 * inv;
            s[ia][1][rr] = e1 * inv;
        }
    // ---- P -> LDS (C/D layout -> row-major) ----
#pragma unroll
    for (int ia = 0; ia < 2; ia++)
#pragma unroll
        for (int jb = 0; jb < 2; jb++)
#pragma unroll
            for (int rr = 0; rr < 4; rr++)
                P[wid][ia * 16 + (lane >> 4) * 4 + rr][jb * 16 + li] = f2bf(s[ia][jb][rr]);
    __syncthreads();
    // ---- PV: ctx[i][d] = sum_j P[i][j] * v[j][d] ----
    short8 pa[2];
    pa[0] = *reinterpret_cast<const short8*>(&P[wid][li][ko]);
    pa[1] = *reinterpret_cast<const short8*>(&P[wid][16 + li][ko]);
    f32x4 o[2][4] = {};
#pragma unroll
    for (int df = 0; df < 4; df++) {
        U8 vb;
#pragma unroll
        for (int jj = 0; jj < 8; jj++) {
            int j = (lane >> 4) * 8 + jj;
            vb.u[jj] = v[((size_t)((j * C_ + c) * N_ + n)) * E_ + h * 64 + df * 16 + li];
        }
#pragma unroll
        for (int ia = 0; ia < 2; ia++)
            o[ia][df] = __builtin_amdgcn_mfma_f32_16x16x32_bf16(pa[ia], vb.v, o[ia][df], 0, 0, 0);
    }
#pragma unroll
    for (int ia = 0; ia < 2; ia++)
#pragma unroll
        for (int df = 0; df < 4; df++)
#pragma unroll
            for (int rr = 0; rr < 4; rr++) {
                int i = ia * 16 + (lane >> 4) * 4 + rr;
                int d = df * 16 + li;
                ctx[((size_t)((i * C_ + c) * N_ + n)) * E_ + h * 64 + d] = f2bf(o[ia][df][rr]);
            }
}

// ---------------- launch ----------------
extern "C" void kernel_launch(void* const* d_in, const int* in_sizes, int n_in,
                              void* d_out, int out_size, void* d_ws, size_t ws_size,
                              hipStream_t stream) {
    const float* x     = (const float*)d_in[0];
    const float* ln_w  = (const float*)d_in[1];
    const float* ln_b  = (const float*)d_in[2];
    const float* row_w = (const float*)d_in[3];
    const float* row_b = (const float*)d_in[4];
    const float* col_w = (const float*)d_in[5];
    const float* col_b = (const float*)d_in[6];
    const float* fc1_w = (const float*)d_in[7];
    const float* fc1_b = (const float*)d_in[8];
    const float* fc2_w = (const float*)d_in[9];
    const float* fc2_b = (const float*)d_in[10];
    float* out = (float*)d_out;

    u16* q_bf = (u16*)d_ws;
    u16* k_bf = q_bf + TE_;
    u16* v_bf = k_bf + TE_;
    u16* h_bf = v_bf + TE_;                   // also ctx
    float* aw = (float*)(h_bf + TE_);         // 48*256*256 fp32
    u16* wrow = (u16*)(aw + (size_t)48 * C_ * C_);
    u16* wcol = wrow + (size_t)4 * E_ * E_;
    u16* wfc1 = wcol + (size_t)4 * E_ * E_;
    u16* wfc2 = wfc1 + (size_t)F_ * E_;
    u16* hid = q_bf;                          // [T][1536] aliases q..k

    const int nW = 4 * E_ * E_;               // 2359296
    cvt_kernel<<<nW / 1024, 256, 0, stream>>>(row_w, wrow, nW);
    cvt_kernel<<<nW / 1024, 256, 0, stream>>>(col_w, wcol, nW);
    cvt_kernel<<<nW / 1024, 256, 0, stream>>>(fc1_w, wfc1, nW);
    cvt_kernel<<<nW / 1024, 256, 0, stream>>>(fc2_w, wfc2, nW);

    // grids: 128 m-tiles x nt_n n-tiles
    const int gQKV = 128 * 9;   // N=2304
    const int gOUT = 128 * 3;   // N=768
    const int gFC1 = 128 * 6;   // N=1536
    const int gFC2 = 128 * 3;   // N=768, K=1536

    // ======== Row self-attention block ========
    ln_kernel<<<T_ / 4, 256, 0, stream>>>(x, ln_w, ln_b, h_bf);
    gemm256<2, false, 24><<<gQKV, 512, 0, stream>>>(h_bf, E_, wrow, E_, row_b, q_bf, E_, nullptr, nullptr, 9);
    row_scores_kernel<<<dim3(16, 48), 256, 0, stream>>>(q_bf, k_bf, aw);
    softmax256_kernel<<<48 * C_ / 4, 256, 0, stream>>>(aw);
    row_ctx_kernel<<<dim3(4, 32, 48), 256, 0, stream>>>(aw, v_bf, h_bf);
    gemm256<1, false, 24><<<gOUT, 512, 0, stream>>>(h_bf, E_, wrow + (size_t)3 * E_ * E_, E_, row_b + 3 * E_, nullptr, E_, out, x, 3);

    // ======== Column self-attention block ========
    ln_kernel<<<T_ / 4, 256, 0, stream>>>(out, ln_w + E_, ln_b + E_, h_bf);
    gemm256<2, false, 24><<<gQKV, 512, 0, stream>>>(h_bf, E_, wcol, E_, col_b, q_bf, E_, nullptr, nullptr, 9);
    col_attn_kernel<<<(H_ * C_ * N_) / 4, 256, 0, stream>>>(q_bf, k_bf, v_bf, h_bf);
    gemm256<1, false, 24><<<gOUT, 512, 0, stream>>>(h_bf, E_, wcol + (size_t)3 * E_ * E_, E_, col_b + 3 * E_, nullptr, E_, out, out, 3);

    // ======== FFN block (two K/N=1536 halves; hidden aliases q..k) ========
    ln_kernel<<<T_ / 4, 256, 0, stream>>>(out, ln_w + 2 * E_, ln_b + 2 * E_, h_bf);
    gemm256<0, true, 24><<<gFC1, 512, 0, stream>>>(h_bf, E_, wfc1, E_, fc1_b, hid, 1536, nullptr, nullptr, 6);
    gemm256<1, false, 48><<<gFC2, 512, 0, stream>>>(hid, 1536, wfc2, F_, fc2_b, nullptr, E_, out, out, 3);
    gemm256<0, true, 24><<<gFC1, 512, 0, stream>>>(h_bf, E_, wfc1 + (size_t)1536 * E_, E_, fc1_b + 1536, hid, 1536, nullptr, nullptr, 6);
    gemm256<1, false, 48><<<gFC2, 512, 0, stream>>>(hid, 1536, wfc2 + 1536, F_, nullptr, nullptr, E_, out, out, 3);
}

// Round 4
// 1253.292 us; speedup vs baseline: 1.5297x; 1.0314x over previous
//
#include <hip/hip_runtime.h>
#include <hip/hip_bf16.h>
#include <math.h>

typedef unsigned short u16;
typedef __attribute__((ext_vector_type(8))) short short8;
typedef __attribute__((ext_vector_type(4))) float f32x4;

#define E_ 768
#define H_ 12
#define D_ 64
#define C_ 256
#define R_ 32
#define N_ 4
#define F_ 3072
#define T_ 32768   // R_*C_*N_
#define TE_ ((size_t)T_ * E_)

union U8 { u16 u[8]; short8 v; };

__device__ __forceinline__ u16 f2bf(float f) {
    unsigned u = __builtin_bit_cast(unsigned, f);
    u = (u + 0x7FFFu + ((u >> 16) & 1u)) >> 16;
    return (u16)u;
}
__device__ __forceinline__ float bf2f(u16 h) {
    unsigned u = ((unsigned)h) << 16;
    return __builtin_bit_cast(float, u);
}

__device__ __forceinline__ void gload_lds16(const u16* g, u16* l) {
    __builtin_amdgcn_global_load_lds((const __attribute__((address_space(1))) void*)g,
                                     (__attribute__((address_space(3))) void*)l, 16, 0, 0);
}

// ---------------- fp32 -> bf16 weight convert ----------------
__global__ __launch_bounds__(256) void cvt_kernel(const float* __restrict__ src,
                                                  u16* __restrict__ dst, int n) {
    int i = (blockIdx.x * 256 + threadIdx.x) * 4;
    if (i >= n) return;
    float4 v = *reinterpret_cast<const float4*>(src + i);
    ushort4 o;
    o.x = f2bf(v.x); o.y = f2bf(v.y); o.z = f2bf(v.z); o.w = f2bf(v.w);
    *reinterpret_cast<ushort4*>(dst + i) = o;
}

// ---------------- LayerNorm: one wave per token (E=768) ----------------
__global__ __launch_bounds__(256) void ln_kernel(const float* __restrict__ x,
                                                 const float* __restrict__ w,
                                                 const float* __restrict__ b,
                                                 u16* __restrict__ out) {
    int wid = threadIdx.x >> 6, lane = threadIdx.x & 63;
    size_t t = (size_t)blockIdx.x * 4 + wid;
    const float* xp = x + t * E_;
    float4 v[3];
    float s1 = 0.f, s2 = 0.f;
#pragma unroll
    for (int c = 0; c < 3; c++) {
        v[c] = *reinterpret_cast<const float4*>(xp + c * 256 + lane * 4);
        s1 += v[c].x + v[c].y + v[c].z + v[c].w;
        s2 += v[c].x * v[c].x + v[c].y * v[c].y + v[c].z * v[c].z + v[c].w * v[c].w;
    }
#pragma unroll
    for (int off = 32; off >= 1; off >>= 1) {
        s1 += __shfl_xor(s1, off);
        s2 += __shfl_xor(s2, off);
    }
    float mu = s1 * (1.0f / E_);
    float var = s2 * (1.0f / E_) - mu * mu;
    float inv = rsqrtf(var + 1e-12f);
#pragma unroll
    for (int c = 0; c < 3; c++) {
        int e = c * 256 + lane * 4;
        float4 wv = *reinterpret_cast<const float4*>(w + e);
        float4 bv = *reinterpret_cast<const float4*>(b + e);
        ushort4 o;
        o.x = f2bf((v[c].x - mu) * inv * wv.x + bv.x);
        o.y = f2bf((v[c].y - mu) * inv * wv.y + bv.y);
        o.z = f2bf((v[c].z - mu) * inv * wv.z + bv.z);
        o.w = f2bf((v[c].w - mu) * inv * wv.w + bv.w);
        *reinterpret_cast<ushort4*>(out + t * E_ + e) = o;
    }
}

// ============ 256x256 GEMM, 4-phase-per-K-tile schedule (T1..T5) ============
// BK=64. LDS: A = 4 half-slots x 16KB @0, B = 4 half-slots x 16KB @64KB.
// Half h (=2t+s) of operand -> slot h&3. Rows stored 128B each, byte
// col-offset XOR-swizzled by ((row&7)<<4); staging sources pre-inverse-swizzled.
// Per tile: ph0{rdA(mh0)+rdB(nh0) | bar | MM q00 | bar}
//           ph1{rdB(nh1) | bar | MM q01 | bar}
//           ph2{rdA(mh1) + stage B(t+2) | bar | MM q11 | bar}
//           ph3{stage A(t+2) | MM q10 | vmcnt(8) | bar}
// MODE 0: bf16 store (opt GELU). 1: fp32 resid add. 2: qkv 3-way split store.
template<int MODE, bool GELU, int NT>
__global__ __launch_bounds__(512, 1) void gemm256p(
    const u16* __restrict__ A, int lda,
    const u16* __restrict__ W, int ldw,
    const float* __restrict__ bias,
    u16* __restrict__ dstB, int ldd,
    float* __restrict__ dstF, const float* __restrict__ resid,
    int nt_n) {
    static_assert(NT >= 4, "need >=4 K-tiles");
    __shared__ u16 lds[65536];   // 128 KB
    const int tid = threadIdx.x;
    const int w8 = tid >> 6, lane = tid & 63;
    const int wm = w8 >> 2, wn = w8 & 3;
    const int li = lane & 15, hi = lane >> 4;

    // T1: XCD-contiguous swizzle + supergroups of 8 m-tiles (n-inner)
    int nwg = gridDim.x;
    int cpx = nwg >> 3;
    int lbid = (blockIdx.x & 7) * cpx + (blockIdx.x >> 3);
    int sgsz = nt_n << 3;
    int sg = lbid / sgsz, rem = lbid - sg * sgsz;
    int nt = rem >> 3, mt = (sg << 3) + (rem & 7);
    int m0 = mt << 8, n0 = nt << 8;

    // staging source (inverse swizzle): thread covers rows (tid>>3) and +64
    const int srow = tid >> 3;
    const int cel = ((((tid & 7) * 16) ^ (((tid >> 3) & 7) << 4)) >> 1);
    const u16* gA00 = A + (size_t)(m0 +       srow) * lda + cel;
    const u16* gA01 = A + (size_t)(m0 +  64 + srow) * lda + cel;
    const u16* gA10 = A + (size_t)(m0 + 128 + srow) * lda + cel;
    const u16* gA11 = A + (size_t)(m0 + 192 + srow) * lda + cel;
    const u16* gB00 = W + (size_t)(n0 +       srow) * ldw + cel;
    const u16* gB01 = W + (size_t)(n0 +  64 + srow) * ldw + cel;
    const u16* gB10 = W + (size_t)(n0 + 128 + srow) * ldw + cel;
    const u16* gB11 = W + (size_t)(n0 + 192 + srow) * ldw + cel;
    const int dst8 = tid * 8;     // u16 index of this thread's 16B stage slot

    // frag read offsets (u16 units) inside a half-slot
    const int c0 = (hi ^ (li & 7)) * 8;
    const int c1 = ((4 | hi) ^ (li & 7)) * 8;
    const int aR = li * 64;
    const int bR = (wn & 1) * 4096 + li * 64;

    short8 af[4][2], bf0[2][2], bf1[2][2];
    f32x4 acc[8][4] = {};

#define STG_A0(t) { int sl_ = (((2*(t)) & 3) * 8192) + dst8;             \
        gload_lds16(gA00 + (t) * 64, lds + sl_);                         \
        gload_lds16(gA01 + (t) * 64, lds + sl_ + 4096); }
#define STG_A1(t) { int sl_ = (((2*(t)+1) & 3) * 8192) + dst8;           \
        gload_lds16(gA10 + (t) * 64, lds + sl_);                         \
        gload_lds16(gA11 + (t) * 64, lds + sl_ + 4096); }
#define STG_B0(t) { int sl_ = 32768 + (((2*(t)) & 3) * 8192) + dst8;     \
        gload_lds16(gB00 + (t) * 64, lds + sl_);                         \
        gload_lds16(gB01 + (t) * 64, lds + sl_ + 4096); }
#define STG_B1(t) { int sl_ = 32768 + (((2*(t)+1) & 3) * 8192) + dst8;   \
        gload_lds16(gB10 + (t) * 64, lds + sl_);                         \
        gload_lds16(gB11 + (t) * 64, lds + sl_ + 4096); }

#define RD_A(t, mh) { const u16* sa_ = lds + ((2*(t)+wm) & 3) * 8192 + (mh) * 4096 + aR; \
        _Pragma("unroll") for (int m4 = 0; m4 < 4; m4++) {               \
            af[m4][0] = *reinterpret_cast<const short8*>(sa_ + m4 * 1024 + c0); \
            af[m4][1] = *reinterpret_cast<const short8*>(sa_ + m4 * 1024 + c1); } }
#define RD_B(t, nh, dst_) { const u16* sb_ = lds + 32768 + ((2*(t)+(wn>>1)) & 3) * 8192 + bR; \
        _Pragma("unroll") for (int n2 = 0; n2 < 2; n2++) {               \
            dst_[n2][0] = *reinterpret_cast<const short8*>(sb_ + ((nh)*2+n2) * 1024 + c0); \
            dst_[n2][1] = *reinterpret_cast<const short8*>(sb_ + ((nh)*2+n2) * 1024 + c1); } }

#define MM(mh, nh, bfr) { __builtin_amdgcn_sched_barrier(0);             \
        __builtin_amdgcn_s_setprio(1);                                   \
        _Pragma("unroll") for (int m4 = 0; m4 < 4; m4++)                 \
        _Pragma("unroll") for (int n2 = 0; n2 < 2; n2++)                 \
        _Pragma("unroll") for (int kk = 0; kk < 2; kk++)                 \
            acc[(mh)*4+m4][(nh)*2+n2] = __builtin_amdgcn_mfma_f32_16x16x32_bf16( \
                af[m4][kk], bfr[n2][kk], acc[(mh)*4+m4][(nh)*2+n2], 0, 0, 0); \
        __builtin_amdgcn_s_setprio(0); __builtin_amdgcn_sched_barrier(0); }

#define BAR() asm volatile("s_barrier" ::: "memory")

#define TILE(t, STG, VMS) {                                              \
        RD_A(t, 0); RD_B(t, 0, bf0);                                     \
        BAR(); MM(0, 0, bf0); BAR();                                     \
        RD_B(t, 1, bf1);                                                 \
        BAR(); MM(0, 1, bf1); BAR();                                     \
        RD_A(t, 1); if (STG) { STG_B0((t)+2); STG_B1((t)+2); }           \
        BAR(); MM(1, 1, bf1); BAR();                                     \
        if (STG) { STG_A0((t)+2); STG_A1((t)+2); }                       \
        MM(1, 0, bf0);                                                   \
        asm volatile(VMS ::: "memory"); BAR(); }

    // prologue: tiles 0 and 1
    STG_A0(0); STG_A1(0); STG_B0(0); STG_B1(0);
    STG_A0(1); STG_A1(1); STG_B0(1); STG_B1(1);
    asm volatile("s_waitcnt vmcnt(8)\ns_barrier" ::: "memory");

#pragma unroll 1
    for (int t = 0; t < NT - 2; ++t)
        TILE(t, 1, "s_waitcnt vmcnt(8)");
    TILE(NT - 2, 0, "s_waitcnt vmcnt(0)");
    TILE(NT - 1, 0, "s_nop 0");

#undef TILE
#undef BAR
#undef MM
#undef RD_B
#undef RD_A
#undef STG_B1
#undef STG_B0
#undef STG_A1
#undef STG_A0

    // ---- epilogue ----
#pragma unroll
    for (int mf = 0; mf < 8; mf++)
#pragma unroll
        for (int nf = 0; nf < 4; nf++) {
            int n = n0 + wn * 64 + nf * 16 + li;
            float bn = bias ? bias[n] : 0.0f;
#pragma unroll
            for (int r = 0; r < 4; r++) {
                int m = m0 + wm * 128 + mf * 16 + hi * 4 + r;
                float vv = acc[mf][nf][r] + bn;
                if (GELU) vv = 0.5f * vv * (1.0f + erff(vv * 0.70710678118654752f));
                if (MODE == 0) {
                    dstB[(size_t)m * ldd + n] = f2bf(vv);
                } else if (MODE == 1) {
                    dstF[(size_t)m * E_ + n] = resid[(size_t)m * E_ + n] + vv;
                } else {
                    int third = (n >= 1536) ? 2 : ((n >= 768) ? 1 : 0);
                    dstB[(size_t)third * TE_ + (size_t)m * E_ + (n - third * 768)] = f2bf(vv);
                }
            }
        }
}

// ---------------- Row-attention scores: aw[h,n,i,j] = s * sum_{r,d} q·k ----------------
__global__ __launch_bounds__(256) void row_scores_kernel(const u16* __restrict__ q,
                                                         const u16* __restrict__ k,
                                                         float* __restrict__ aw) {
    int tile = blockIdx.x;            // 16: 4 i-tiles x 4 j-tiles
    int hn = blockIdx.y;              // 48
    int h = hn >> 2, n = hn & 3;
    int i0 = (tile >> 2) * 64, j0 = (tile & 3) * 64;
    int wid = threadIdx.x >> 6, lane = threadIdx.x & 63;
    int wy = wid >> 1, wx = wid & 1;
    int iW = i0 + wy * 32, jW = j0 + wx * 32;
    int li = lane & 15, ko = (lane >> 4) * 8;

    f32x4 acc[2][2] = {};
    for (int r = 0; r < R_; r++) {
#pragma unroll
        for (int d0 = 0; d0 < 64; d0 += 32) {
            short8 aq[2], ak[2];
#pragma unroll
            for (int mi = 0; mi < 2; mi++) {
                size_t oq = ((size_t)((r * C_ + iW + mi * 16 + li) * N_ + n)) * E_ + h * 64 + d0 + ko;
                aq[mi] = *reinterpret_cast<const short8*>(q + oq);
                size_t ok = ((size_t)((r * C_ + jW + mi * 16 + li) * N_ + n)) * E_ + h * 64 + d0 + ko;
                ak[mi] = *reinterpret_cast<const short8*>(k + ok);
            }
#pragma unroll
            for (int mi = 0; mi < 2; mi++)
#pragma unroll
                for (int ni = 0; ni < 2; ni++)
                    acc[mi][ni] = __builtin_amdgcn_mfma_f32_16x16x32_bf16(aq[mi], ak[ni], acc[mi][ni], 0, 0, 0);
        }
    }
    const float scale = 0.02209708691207961f;  // (1/8) / sqrt(32)
#pragma unroll
    for (int mi = 0; mi < 2; mi++)
#pragma unroll
        for (int ni = 0; ni < 2; ni++)
#pragma unroll
            for (int r = 0; r < 4; r++) {
                int i = iW + mi * 16 + (lane >> 4) * 4 + r;
                int j = jW + ni * 16 + li;
                aw[((size_t)hn * C_ + i) * C_ + j] = acc[mi][ni][r] * scale;
            }
}

// ---------------- softmax over rows of length 256, in place ----------------
__global__ __launch_bounds__(256) void softmax256_kernel(float* __restrict__ aw) {
    int wid = threadIdx.x >> 6, lane = threadIdx.x & 63;
    size_t row = (size_t)blockIdx.x * 4 + wid;
    float* p = aw + row * 256;
    float4 v = reinterpret_cast<float4*>(p)[lane];
    float m = fmaxf(fmaxf(v.x, v.y), fmaxf(v.z, v.w));
#pragma unroll
    for (int off = 32; off >= 1; off >>= 1) m = fmaxf(m, __shfl_xor(m, off));
    float e0 = expf(v.x - m), e1 = expf(v.y - m), e2 = expf(v.z - m), e3 = expf(v.w - m);
    float s = e0 + e1 + e2 + e3;
#pragma unroll
    for (int off = 32; off >= 1; off >>= 1) s += __shfl_xor(s, off);
    float inv = 1.0f / s;
    float4 o; o.x = e0 * inv; o.y = e1 * inv; o.z = e2 * inv; o.w = e3 * inv;
    reinterpret_cast<float4*>(p)[lane] = o;
}

// ---------------- Row-attention AP·V: ctx[r,i,n,h,d] ----------------
__global__ __launch_bounds__(256) void row_ctx_kernel(const float* __restrict__ ap,
                                                      const u16* __restrict__ v,
                                                      u16* __restrict__ ctx) {
    int i0 = blockIdx.x * 64;     // 4 tiles
    int r = blockIdx.y;           // 32
    int hn = blockIdx.z;          // 48
    int h = hn >> 2, n = hn & 3;
    __shared__ u16 APs[64][40];
    __shared__ u16 Vts[64][40];   // Vt[d][j]
    int tid = threadIdx.x, wid = tid >> 6, lane = tid & 63;
    int wy = wid >> 1, wx = wid & 1;
    int li = lane & 15, ko = (lane >> 4) * 8;
    int ai = tid >> 2, aj = (tid & 3) * 8;   // AP staging: [64 i][32 j]
    int vj = tid >> 3, vd = (tid & 7) * 8;   // V staging: 32 j rows, 8 d each

    f32x4 acc[2][2] = {};
    for (int j0 = 0; j0 < C_; j0 += 32) {
        const float* aps = ap + ((size_t)hn * C_ + i0 + ai) * C_ + j0 + aj;
        float4 p0 = *reinterpret_cast<const float4*>(aps);
        float4 p1 = *reinterpret_cast<const float4*>(aps + 4);
        U8 t8;
        t8.u[0] = f2bf(p0.x); t8.u[1] = f2bf(p0.y); t8.u[2] = f2bf(p0.z); t8.u[3] = f2bf(p0.w);
        t8.u[4] = f2bf(p1.x); t8.u[5] = f2bf(p1.y); t8.u[6] = f2bf(p1.z); t8.u[7] = f2bf(p1.w);
        *reinterpret_cast<short8*>(&APs[ai][aj]) = t8.v;
        U8 vv;
        vv.v = *reinterpret_cast<const short8*>(
            v + ((size_t)((r * C_ + j0 + vj) * N_ + n)) * E_ + h * 64 + vd);
#pragma unroll
        for (int u = 0; u < 8; u++) Vts[vd + u][vj] = vv.u[u];
        __syncthreads();
        short8 af[2], vf[2];
        af[0] = *reinterpret_cast<const short8*>(&APs[wy * 32 + li][ko]);
        af[1] = *reinterpret_cast<const short8*>(&APs[wy * 32 + 16 + li][ko]);
        vf[0] = *reinterpret_cast<const short8*>(&Vts[wx * 32 + li][ko]);
        vf[1] = *reinterpret_cast<const short8*>(&Vts[wx * 32 + 16 + li][ko]);
#pragma unroll
        for (int mi = 0; mi < 2; mi++)
#pragma unroll
            for (int ni = 0; ni < 2; ni++)
                acc[mi][ni] = __builtin_amdgcn_mfma_f32_16x16x32_bf16(af[mi], vf[ni], acc[mi][ni], 0, 0, 0);
        __syncthreads();
    }
#pragma unroll
    for (int mi = 0; mi < 2; mi++)
#pragma unroll
        for (int ni = 0; ni < 2; ni++)
#pragma unroll
            for (int rr = 0; rr < 4; rr++) {
                int i = i0 + wy * 32 + mi * 16 + (lane >> 4) * 4 + rr;
                int d = wx * 32 + ni * 16 + li;
                ctx[((size_t)((r * C_ + i) * N_ + n)) * E_ + h * 64 + d] = f2bf(acc[mi][ni][rr]);
            }
}

// ---------------- Column attention, fully fused: one wave per (h,c,n) ----------------
__global__ __launch_bounds__(256) void col_attn_kernel(const u16* __restrict__ q,
                                                       const u16* __restrict__ k,
                                                       const u16* __restrict__ v,
                                                       u16* __restrict__ ctx) {
    __shared__ u16 P[4][32][40];
    int wid = threadIdx.x >> 6, lane = threadIdx.x & 63;
    int g = blockIdx.x * 4 + wid;        // 12288 = H * C * N
    int h = g >> 10;
    int cn = g & 1023;
    int c = cn >> 2, n = cn & 3;
    int li = lane & 15, ko = (lane >> 4) * 8;

    // ---- scores S[i][j] over rows i,j in [0,32), K = d = 64 ----
    f32x4 s[2][2] = {};
#pragma unroll
    for (int d0 = 0; d0 < 64; d0 += 32) {
        short8 aq[2], ak[2];
#pragma unroll
        for (int ia = 0; ia < 2; ia++) {
            size_t oq = ((size_t)(((ia * 16 + li) * C_ + c) * N_ + n)) * E_ + h * 64 + d0 + ko;
            aq[ia] = *reinterpret_cast<const short8*>(q + oq);
            ak[ia] = *reinterpret_cast<const short8*>(k + oq);  // same index formula for k
        }
#pragma unroll
        for (int ia = 0; ia < 2; ia++)
#pragma unroll
            for (int jb = 0; jb < 2; jb++)
                s[ia][jb] = __builtin_amdgcn_mfma_f32_16x16x32_bf16(aq[ia], ak[jb], s[ia][jb], 0, 0, 0);
    }
    // ---- softmax over j (32 values per row i) ----
#pragma unroll
    for (int ia = 0; ia < 2; ia++)
#pragma unroll
        for (int rr = 0; rr < 4; rr++) {
            float a0 = s[ia][0][rr] * 0.125f;
            float a1 = s[ia][1][rr] * 0.125f;
            float m = fmaxf(a0, a1);
#pragma unroll
            for (int off = 8; off >= 1; off >>= 1) m = fmaxf(m, __shfl_xor(m, off));
            float e0 = expf(a0 - m), e1 = expf(a1 - m);
            float ss = e0 + e1;
#pragma unroll
            for (int off = 8; off >= 1; off >>= 1) ss += __shfl_xor(ss, off);
            float inv = 1.0f / ss;
            s[ia][0][rr] = e0 * inv;
            s[ia][1][rr] = e1 * inv;
        }
    // ---- P -> LDS (C/D layout -> row-major) ----
#pragma unroll
    for (int ia = 0; ia < 2; ia++)
#pragma unroll
        for (int jb = 0; jb < 2; jb++)
#pragma unroll
            for (int rr = 0; rr < 4; rr++)
                P[wid][ia * 16 + (lane >> 4) * 4 + rr][jb * 16 + li] = f2bf(s[ia][jb][rr]);
    __syncthreads();
    // ---- PV: ctx[i][d] = sum_j P[i][j] * v[j][d] ----
    short8 pa[2];
    pa[0] = *reinterpret_cast<const short8*>(&P[wid][li][ko]);
    pa[1] = *reinterpret_cast<const short8*>(&P[wid][16 + li][ko]);
    f32x4 o[2][4] = {};
#pragma unroll
    for (int df = 0; df < 4; df++) {
        U8 vb;
#pragma unroll
        for (int jj = 0; jj < 8; jj++) {
            int j = (lane >> 4) * 8 + jj;
            vb.u[jj] = v[((size_t)((j * C_ + c) * N_ + n)) * E_ + h * 64 + df * 16 + li];
        }
#pragma unroll
        for (int ia = 0; ia < 2; ia++)
            o[ia][df] = __builtin_amdgcn_mfma_f32_16x16x32_bf16(pa[ia], vb.v, o[ia][df], 0, 0, 0);
    }
#pragma unroll
    for (int ia = 0; ia < 2; ia++)
#pragma unroll
        for (int df = 0; df < 4; df++)
#pragma unroll
            for (int rr = 0; rr < 4; rr++) {
                int i = ia * 16 + (lane >> 4) * 4 + rr;
                int d = df * 16 + li;
                ctx[((size_t)((i * C_ + c) * N_ + n)) * E_ + h * 64 + d] = f2bf(o[ia][df][rr]);
            }
}

// ---------------- launch ----------------
extern "C" void kernel_launch(void* const* d_in, const int* in_sizes, int n_in,
                              void* d_out, int out_size, void* d_ws, size_t ws_size,
                              hipStream_t stream) {
    const float* x     = (const float*)d_in[0];
    const float* ln_w  = (const float*)d_in[1];
    const float* ln_b  = (const float*)d_in[2];
    const float* row_w = (const float*)d_in[3];
    const float* row_b = (const float*)d_in[4];
    const float* col_w = (const float*)d_in[5];
    const float* col_b = (const float*)d_in[6];
    const float* fc1_w = (const float*)d_in[7];
    const float* fc1_b = (const float*)d_in[8];
    const float* fc2_w = (const float*)d_in[9];
    const float* fc2_b = (const float*)d_in[10];
    float* out = (float*)d_out;

    u16* q_bf = (u16*)d_ws;
    u16* k_bf = q_bf + TE_;
    u16* v_bf = k_bf + TE_;
    u16* h_bf = v_bf + TE_;                   // also ctx
    float* aw = (float*)(h_bf + TE_);         // 48*256*256 fp32
    u16* wrow = (u16*)(aw + (size_t)48 * C_ * C_);
    u16* wcol = wrow + (size_t)4 * E_ * E_;
    u16* wfc1 = wcol + (size_t)4 * E_ * E_;
    u16* wfc2 = wfc1 + (size_t)F_ * E_;
    u16* hid = q_bf;                          // [T][1536] aliases q..k

    const int nW = 4 * E_ * E_;               // 2359296
    cvt_kernel<<<nW / 1024, 256, 0, stream>>>(row_w, wrow, nW);
    cvt_kernel<<<nW / 1024, 256, 0, stream>>>(col_w, wcol, nW);
    cvt_kernel<<<nW / 1024, 256, 0, stream>>>(fc1_w, wfc1, nW);
    cvt_kernel<<<nW / 1024, 256, 0, stream>>>(fc2_w, wfc2, nW);

    // grids: 128 m-tiles x nt_n n-tiles
    const int gQKV = 128 * 9;   // N=2304
    const int gOUT = 128 * 3;   // N=768
    const int gFC1 = 128 * 6;   // N=1536
    const int gFC2 = 128 * 3;   // N=768, K=1536

    // ======== Row self-attention block ========
    ln_kernel<<<T_ / 4, 256, 0, stream>>>(x, ln_w, ln_b, h_bf);
    gemm256p<2, false, 12><<<gQKV, 512, 0, stream>>>(h_bf, E_, wrow, E_, row_b, q_bf, E_, nullptr, nullptr, 9);
    row_scores_kernel<<<dim3(16, 48), 256, 0, stream>>>(q_bf, k_bf, aw);
    softmax256_kernel<<<48 * C_ / 4, 256, 0, stream>>>(aw);
    row_ctx_kernel<<<dim3(4, 32, 48), 256, 0, stream>>>(aw, v_bf, h_bf);
    gemm256p<1, false, 12><<<gOUT, 512, 0, stream>>>(h_bf, E_, wrow + (size_t)3 * E_ * E_, E_, row_b + 3 * E_, nullptr, E_, out, x, 3);

    // ======== Column self-attention block ========
    ln_kernel<<<T_ / 4, 256, 0, stream>>>(out, ln_w + E_, ln_b + E_, h_bf);
    gemm256p<2, false, 12><<<gQKV, 512, 0, stream>>>(h_bf, E_, wcol, E_, col_b, q_bf, E_, nullptr, nullptr, 9);
    col_attn_kernel<<<(H_ * C_ * N_) / 4, 256, 0, stream>>>(q_bf, k_bf, v_bf, h_bf);
    gemm256p<1, false, 12><<<gOUT, 512, 0, stream>>>(h_bf, E_, wcol + (size_t)3 * E_ * E_, E_, col_b + 3 * E_, nullptr, E_, out, out, 3);

    // ======== FFN block (two K/N=1536 halves; hidden aliases q..k) ========
    ln_kernel<<<T_ / 4, 256, 0, stream>>>(out, ln_w + 2 * E_, ln_b + 2 * E_, h_bf);
    gemm256p<0, true, 12><<<gFC1, 512, 0, stream>>>(h_bf, E_, wfc1, E_, fc1_b, hid, 1536, nullptr, nullptr, 6);
    gemm256p<1, false, 24><<<gFC2, 512, 0, stream>>>(hid, 1536, wfc2, F_, fc2_b, nullptr, E_, out, out, 3);
    gemm256p<0, true, 12><<<gFC1, 512, 0, stream>>>(h_bf, E_, wfc1 + (size_t)1536 * E_, E_, fc1_b + 1536, hid, 1536, nullptr, nullptr, 6);
    gemm256p<1, false, 24><<<gFC2, 512, 0, stream>>>(hid, 1536, wfc2 + 1536, F_, nullptr, nullptr, E_, out, out, 3);
}

// Round 6
// 1246.577 us; speedup vs baseline: 1.5379x; 1.0054x over previous
//
#include <hip/hip_runtime.h>
#include <hip/hip_bf16.h>
#include <math.h>

typedef unsigned short u16;
typedef __attribute__((ext_vector_type(8))) short short8;
typedef __attribute__((ext_vector_type(4))) float f32x4;

#define E_ 768
#define H_ 12
#define D_ 64
#define C_ 256
#define R_ 32
#define N_ 4
#define F_ 3072
#define T_ 32768   // R_*C_*N_
#define TE_ ((size_t)T_ * E_)
#define PL_ ((size_t)R_ * C_ * 64)   // one (h,n) plane of q/k/v

union U8 { u16 u[8]; short8 v; };

__device__ __forceinline__ u16 f2bf(float f) {
    unsigned u = __builtin_bit_cast(unsigned, f);
    u = (u + 0x7FFFu + ((u >> 16) & 1u)) >> 16;
    return (u16)u;
}
__device__ __forceinline__ float bf2f(u16 h) {
    unsigned u = ((unsigned)h) << 16;
    return __builtin_bit_cast(float, u);
}

__device__ __forceinline__ void gload_lds16(const u16* g, u16* l) {
    __builtin_amdgcn_global_load_lds((const __attribute__((address_space(1))) void*)g,
                                     (__attribute__((address_space(3))) void*)l, 16, 0, 0);
}

// ---------------- fp32 -> bf16 weight convert ----------------
__global__ __launch_bounds__(256) void cvt_kernel(const float* __restrict__ src,
                                                  u16* __restrict__ dst, int n) {
    int i = (blockIdx.x * 256 + threadIdx.x) * 4;
    if (i >= n) return;
    float4 v = *reinterpret_cast<const float4*>(src + i);
    ushort4 o;
    o.x = f2bf(v.x); o.y = f2bf(v.y); o.z = f2bf(v.z); o.w = f2bf(v.w);
    *reinterpret_cast<ushort4*>(dst + i) = o;
}

// ---------------- LayerNorm: one wave per token (E=768) ----------------
__global__ __launch_bounds__(256) void ln_kernel(const float* __restrict__ x,
                                                 const float* __restrict__ w,
                                                 const float* __restrict__ b,
                                                 u16* __restrict__ out) {
    int wid = threadIdx.x >> 6, lane = threadIdx.x & 63;
    size_t t = (size_t)blockIdx.x * 4 + wid;
    const float* xp = x + t * E_;
    float4 v[3];
    float s1 = 0.f, s2 = 0.f;
#pragma unroll
    for (int c = 0; c < 3; c++) {
        v[c] = *reinterpret_cast<const float4*>(xp + c * 256 + lane * 4);
        s1 += v[c].x + v[c].y + v[c].z + v[c].w;
        s2 += v[c].x * v[c].x + v[c].y * v[c].y + v[c].z * v[c].z + v[c].w * v[c].w;
    }
#pragma unroll
    for (int off = 32; off >= 1; off >>= 1) {
        s1 += __shfl_xor(s1, off);
        s2 += __shfl_xor(s2, off);
    }
    float mu = s1 * (1.0f / E_);
    float var = s2 * (1.0f / E_) - mu * mu;
    float inv = rsqrtf(var + 1e-12f);
#pragma unroll
    for (int c = 0; c < 3; c++) {
        int e = c * 256 + lane * 4;
        float4 wv = *reinterpret_cast<const float4*>(w + e);
        float4 bv = *reinterpret_cast<const float4*>(b + e);
        ushort4 o;
        o.x = f2bf((v[c].x - mu) * inv * wv.x + bv.x);
        o.y = f2bf((v[c].y - mu) * inv * wv.y + bv.y);
        o.z = f2bf((v[c].z - mu) * inv * wv.z + bv.z);
        o.w = f2bf((v[c].w - mu) * inv * wv.w + bv.w);
        *reinterpret_cast<ushort4*>(out + t * E_ + e) = o;
    }
}

// ===== 256x256 GEMM, 4-phase schedule; R4-proven stage placement =====
// BK=64. LDS: A = 4 half-slots x 16KB @0, B = 4 half-slots x 16KB @64KB.
// A slot (2t+wm)&3 holds M-rows wm*128..wm*128+127 (LIVE through ph0..ph2!).
// Stage placement (slot-liveness-safe, == R4): B(t+2) in ph2 (B reads retire
// at ph1-end barrier), A(t+2) in ph3 (A reads retire at ph2's lgkmcnt+barrier).
// No sched_barrier; builtin s_barrier wrapped in zero-cost compiler fences
// (builtin is IntrNoMem -> LLVM may otherwise hoist LDS reads across it).
// vmcnt(8) once per tile (2 tiles in flight), never 0 in main loop.
// MODE 0: bf16 store (opt GELU). 1: fp32 resid add. 2: qkv planar-split store
//         q/k/v[hn][r][c][d] with hn=h*4+ntok.
template<int MODE, bool GELU, int NT>
__global__ __launch_bounds__(512, 1) void gemm256p(
    const u16* __restrict__ A, int lda,
    const u16* __restrict__ W, int ldw,
    const float* __restrict__ bias,
    u16* __restrict__ dstB, int ldd,
    float* __restrict__ dstF, const float* __restrict__ resid,
    int nt_n) {
    static_assert(NT >= 4, "need >=4 K-tiles");
    __shared__ u16 lds[65536];   // 128 KB
    const int tid = threadIdx.x;
    const int w8 = tid >> 6, lane = tid & 63;
    const int wm = w8 >> 2, wn = w8 & 3;
    const int li = lane & 15, hi = lane >> 4;

    // T1: XCD-contiguous swizzle + supergroups of 8 m-tiles (n-inner)
    int nwg = gridDim.x;
    int cpx = nwg >> 3;
    int lbid = (blockIdx.x & 7) * cpx + (blockIdx.x >> 3);
    int sgsz = nt_n << 3;
    int sg = lbid / sgsz, rem = lbid - sg * sgsz;
    int nt = rem >> 3, mt = (sg << 3) + (rem & 7);
    int m0 = mt << 8, n0 = nt << 8;

    // staging source (inverse swizzle): thread covers rows (tid>>3) and +64
    const int srow = tid >> 3;
    const int cel = ((((tid & 7) * 16) ^ (((tid >> 3) & 7) << 4)) >> 1);
    const u16* gA00 = A + (size_t)(m0 +       srow) * lda + cel;
    const u16* gA01 = A + (size_t)(m0 +  64 + srow) * lda + cel;
    const u16* gA10 = A + (size_t)(m0 + 128 + srow) * lda + cel;
    const u16* gA11 = A + (size_t)(m0 + 192 + srow) * lda + cel;
    const u16* gB00 = W + (size_t)(n0 +       srow) * ldw + cel;
    const u16* gB01 = W + (size_t)(n0 +  64 + srow) * ldw + cel;
    const u16* gB10 = W + (size_t)(n0 + 128 + srow) * ldw + cel;
    const u16* gB11 = W + (size_t)(n0 + 192 + srow) * ldw + cel;
    const int dst8 = tid * 8;     // u16 index of this thread's 16B stage slot

    // frag read offsets (u16 units) inside a half-slot
    const int c0 = (hi ^ (li & 7)) * 8;
    const int c1 = ((4 | hi) ^ (li & 7)) * 8;
    const int aR = li * 64;
    const int bR = (wn & 1) * 4096 + li * 64;

    short8 af[4][2], bf0[2][2], bf1[2][2];
    f32x4 acc[8][4] = {};

#define STG_A0(t) { int sl_ = (((2*(t)) & 3) * 8192) + dst8;             \
        gload_lds16(gA00 + (t) * 64, lds + sl_);                         \
        gload_lds16(gA01 + (t) * 64, lds + sl_ + 4096); }
#define STG_A1(t) { int sl_ = (((2*(t)+1) & 3) * 8192) + dst8;           \
        gload_lds16(gA10 + (t) * 64, lds + sl_);                         \
        gload_lds16(gA11 + (t) * 64, lds + sl_ + 4096); }
#define STG_B0(t) { int sl_ = 32768 + (((2*(t)) & 3) * 8192) + dst8;     \
        gload_lds16(gB00 + (t) * 64, lds + sl_);                         \
        gload_lds16(gB01 + (t) * 64, lds + sl_ + 4096); }
#define STG_B1(t) { int sl_ = 32768 + (((2*(t)+1) & 3) * 8192) + dst8;   \
        gload_lds16(gB10 + (t) * 64, lds + sl_);                         \
        gload_lds16(gB11 + (t) * 64, lds + sl_ + 4096); }

#define RD_A(t, mh) { const u16* sa_ = lds + ((2*(t)+wm) & 3) * 8192 + (mh) * 4096 + aR; \
        _Pragma("unroll") for (int m4 = 0; m4 < 4; m4++) {               \
            af[m4][0] = *reinterpret_cast<const short8*>(sa_ + m4 * 1024 + c0); \
            af[m4][1] = *reinterpret_cast<const short8*>(sa_ + m4 * 1024 + c1); } }
#define RD_B(t, nh, dst_) { const u16* sb_ = lds + 32768 + ((2*(t)+(wn>>1)) & 3) * 8192 + bR; \
        _Pragma("unroll") for (int n2 = 0; n2 < 2; n2++) {               \
            dst_[n2][0] = *reinterpret_cast<const short8*>(sb_ + ((nh)*2+n2) * 1024 + c0); \
            dst_[n2][1] = *reinterpret_cast<const short8*>(sb_ + ((nh)*2+n2) * 1024 + c1); } }

#define MM(mh, nh, bfr) {                                                \
        __builtin_amdgcn_s_setprio(1);                                   \
        _Pragma("unroll") for (int m4 = 0; m4 < 4; m4++)                 \
        _Pragma("unroll") for (int n2 = 0; n2 < 2; n2++)                 \
        _Pragma("unroll") for (int kk = 0; kk < 2; kk++)                 \
            acc[(mh)*4+m4][(nh)*2+n2] = __builtin_amdgcn_mfma_f32_16x16x32_bf16( \
                af[m4][kk], bfr[n2][kk], acc[(mh)*4+m4][(nh)*2+n2], 0, 0, 0); \
        __builtin_amdgcn_s_setprio(0); }

#define BARR() { asm volatile("" ::: "memory");                          \
                 __builtin_amdgcn_s_barrier();                           \
                 asm volatile("" ::: "memory"); }
#define LGK0() asm volatile("s_waitcnt lgkmcnt(0)" ::: "memory")
#define VMW8() asm volatile("s_waitcnt vmcnt(8)" ::: "memory")
#define VMW0() asm volatile("s_waitcnt vmcnt(0)" ::: "memory")

#define TILE(t, S, VMS) {                                                \
        /* ph0 */                                                        \
        RD_A(t, 0); RD_B(t, 0, bf0);                                     \
        BARR(); LGK0();                                                  \
        MM(0, 0, bf0);                                                   \
        BARR();                                                          \
        /* ph1 */                                                        \
        RD_B(t, 1, bf1);                                                 \
        BARR(); LGK0();                                                  \
        MM(0, 1, bf1);                                                   \
        BARR();                                                          \
        /* ph2: B reads retired at ph1-end barrier -> B(t+2) safe */     \
        RD_A(t, 1);                                                      \
        if (S) { STG_B0((t)+2); STG_B1((t)+2); }                         \
        BARR(); LGK0();                                                  \
        MM(1, 1, bf1);                                                   \
        BARR();                                                          \
        /* ph3: A reads retired at ph2 lgkmcnt+barrier -> A(t+2) safe */ \
        if (S) { STG_A0((t)+2); STG_A1((t)+2); }                         \
        MM(1, 0, bf0);                                                   \
        VMS;                                                             \
        BARR(); }

    // prologue: tiles 0 and 1
    STG_A0(0); STG_A1(0); STG_B0(0); STG_B1(0);
    STG_A0(1); STG_A1(1); STG_B0(1); STG_B1(1);
    VMW8(); BARR();

#pragma unroll 1
    for (int t = 0; t < NT - 2; ++t)
        TILE(t, 1, VMW8());
    TILE(NT - 2, 0, VMW0());
    TILE(NT - 1, 0, (void)0);

#undef TILE
#undef BARR
#undef LGK0
#undef VMW8
#undef VMW0
#undef MM
#undef RD_B
#undef RD_A
#undef STG_B1
#undef STG_B0
#undef STG_A1
#undef STG_A0

    // ---- epilogue ----
#pragma unroll
    for (int mf = 0; mf < 8; mf++)
#pragma unroll
        for (int nf = 0; nf < 4; nf++) {
            int n = n0 + wn * 64 + nf * 16 + li;
            float bn = bias ? bias[n] : 0.0f;
#pragma unroll
            for (int r = 0; r < 4; r++) {
                int m = m0 + wm * 128 + mf * 16 + hi * 4 + r;
                float vv = acc[mf][nf][r] + bn;
                if (GELU) vv = 0.5f * vv * (1.0f + erff(vv * 0.70710678118654752f));
                if (MODE == 0) {
                    dstB[(size_t)m * ldd + n] = f2bf(vv);
                } else if (MODE == 1) {
                    dstF[(size_t)m * E_ + n] = resid[(size_t)m * E_ + n] + vv;
                } else {
                    int third = (n >= 1536) ? 2 : ((n >= 768) ? 1 : 0);
                    int rem2 = n - third * 768;
                    int hh = rem2 >> 6, dd = rem2 & 63;
                    int ntok = m & 3, cc = (m >> 2) & 255, rr = m >> 10;
                    dstB[(size_t)third * TE_ +
                         (((size_t)(hh * 4 + ntok) * R_ + rr) * C_ + cc) * 64 + dd] = f2bf(vv);
                }
            }
        }
}

// ---- Row-attention scores (planar q/k): aw[hn,i,j] = s * sum_{r,d} q·k ----
__global__ __launch_bounds__(256) void row_scores_kernel(const u16* __restrict__ q,
                                                         const u16* __restrict__ k,
                                                         float* __restrict__ aw) {
    int tile = blockIdx.x;            // 16: 4 i-tiles x 4 j-tiles
    int hn = blockIdx.y;              // 48
    int i0 = (tile >> 2) * 64, j0 = (tile & 3) * 64;
    int wid = threadIdx.x >> 6, lane = threadIdx.x & 63;
    int wy = wid >> 1, wx = wid & 1;
    int iW = i0 + wy * 32, jW = j0 + wx * 32;
    int li = lane & 15, ko = (lane >> 4) * 8;

    const u16* qp = q + (size_t)hn * PL_;
    const u16* kp = k + (size_t)hn * PL_;

    f32x4 acc[2][2] = {};
    for (int r = 0; r < R_; r++) {
#pragma unroll
        for (int d0 = 0; d0 < 64; d0 += 32) {
            short8 aq[2], ak[2];
#pragma unroll
            for (int mi = 0; mi < 2; mi++) {
                aq[mi] = *reinterpret_cast<const short8*>(qp + ((size_t)(r * C_ + iW + mi * 16 + li)) * 64 + d0 + ko);
                ak[mi] = *reinterpret_cast<const short8*>(kp + ((size_t)(r * C_ + jW + mi * 16 + li)) * 64 + d0 + ko);
            }
#pragma unroll
            for (int mi = 0; mi < 2; mi++)
#pragma unroll
                for (int ni = 0; ni < 2; ni++)
                    acc[mi][ni] = __builtin_amdgcn_mfma_f32_16x16x32_bf16(aq[mi], ak[ni], acc[mi][ni], 0, 0, 0);
        }
    }
    const float scale = 0.02209708691207961f;  // (1/8) / sqrt(32)
#pragma unroll
    for (int mi = 0; mi < 2; mi++)
#pragma unroll
        for (int ni = 0; ni < 2; ni++)
#pragma unroll
            for (int r = 0; r < 4; r++) {
                int i = iW + mi * 16 + (lane >> 4) * 4 + r;
                int j = jW + ni * 16 + li;
                aw[((size_t)hn * C_ + i) * C_ + j] = acc[mi][ni][r] * scale;
            }
}

// ---------------- softmax over rows of length 256, in place ----------------
__global__ __launch_bounds__(256) void softmax256_kernel(float* __restrict__ aw) {
    int wid = threadIdx.x >> 6, lane = threadIdx.x & 63;
    size_t row = (size_t)blockIdx.x * 4 + wid;
    float* p = aw + row * 256;
    float4 v = reinterpret_cast<float4*>(p)[lane];
    float m = fmaxf(fmaxf(v.x, v.y), fmaxf(v.z, v.w));
#pragma unroll
    for (int off = 32; off >= 1; off >>= 1) m = fmaxf(m, __shfl_xor(m, off));
    float e0 = expf(v.x - m), e1 = expf(v.y - m), e2 = expf(v.z - m), e3 = expf(v.w - m);
    float s = e0 + e1 + e2 + e3;
#pragma unroll
    for (int off = 32; off >= 1; off >>= 1) s += __shfl_xor(s, off);
    float inv = 1.0f / s;
    float4 o; o.x = e0 * inv; o.y = e1 * inv; o.z = e2 * inv; o.w = e3 * inv;
    reinterpret_cast<float4*>(p)[lane] = o;
}

// ---- Row-attention AP·V (planar v): ctx[r,i,n,h,d] token-major out ----
__global__ __launch_bounds__(256) void row_ctx_kernel(const float* __restrict__ ap,
                                                      const u16* __restrict__ v,
                                                      u16* __restrict__ ctx) {
    int i0 = blockIdx.x * 64;     // 4 tiles
    int r = blockIdx.y;           // 32
    int hn = blockIdx.z;          // 48
    int h = hn >> 2, n = hn & 3;
    __shared__ u16 APs[64][40];
    __shared__ u16 Vts[64][40];   // Vt[d][j]
    int tid = threadIdx.x, wid = tid >> 6, lane = tid & 63;
    int wy = wid >> 1, wx = wid & 1;
    int li = lane & 15, ko = (lane >> 4) * 8;
    int ai = tid >> 2, aj = (tid & 3) * 8;   // AP staging: [64 i][32 j]
    int vj = tid >> 3, vd = (tid & 7) * 8;   // V staging: 32 j rows, 8 d each

    const u16* vp = v + (size_t)hn * PL_;

    f32x4 acc[2][2] = {};
    for (int j0 = 0; j0 < C_; j0 += 32) {
        const float* aps = ap + ((size_t)hn * C_ + i0 + ai) * C_ + j0 + aj;
        float4 p0 = *reinterpret_cast<const float4*>(aps);
        float4 p1 = *reinterpret_cast<const float4*>(aps + 4);
        U8 t8;
        t8.u[0] = f2bf(p0.x); t8.u[1] = f2bf(p0.y); t8.u[2] = f2bf(p0.z); t8.u[3] = f2bf(p0.w);
        t8.u[4] = f2bf(p1.x); t8.u[5] = f2bf(p1.y); t8.u[6] = f2bf(p1.z); t8.u[7] = f2bf(p1.w);
        *reinterpret_cast<short8*>(&APs[ai][aj]) = t8.v;
        U8 vv;
        vv.v = *reinterpret_cast<const short8*>(vp + ((size_t)(r * C_ + j0 + vj)) * 64 + vd);
#pragma unroll
        for (int u = 0; u < 8; u++) Vts[vd + u][vj] = vv.u[u];
        __syncthreads();
        short8 af[2], vf[2];
        af[0] = *reinterpret_cast<const short8*>(&APs[wy * 32 + li][ko]);
        af[1] = *reinterpret_cast<const short8*>(&APs[wy * 32 + 16 + li][ko]);
        vf[0] = *reinterpret_cast<const short8*>(&Vts[wx * 32 + li][ko]);
        vf[1] = *reinterpret_cast<const short8*>(&Vts[wx * 32 + 16 + li][ko]);
#pragma unroll
        for (int mi = 0; mi < 2; mi++)
#pragma unroll
            for (int ni = 0; ni < 2; ni++)
                acc[mi][ni] = __builtin_amdgcn_mfma_f32_16x16x32_bf16(af[mi], vf[ni], acc[mi][ni], 0, 0, 0);
        __syncthreads();
    }
#pragma unroll
    for (int mi = 0; mi < 2; mi++)
#pragma unroll
        for (int ni = 0; ni < 2; ni++)
#pragma unroll
            for (int rr = 0; rr < 4; rr++) {
                int i = i0 + wy * 32 + mi * 16 + (lane >> 4) * 4 + rr;
                int d = wx * 32 + ni * 16 + li;
                ctx[((size_t)((r * C_ + i) * N_ + n)) * E_ + h * 64 + d] = f2bf(acc[mi][ni][rr]);
            }
}

// ---- Column attention (planar q/k/v), fused: one wave per (h,c,n) ----
__global__ __launch_bounds__(256) void col_attn_kernel(const u16* __restrict__ q,
                                                       const u16* __restrict__ k,
                                                       const u16* __restrict__ v,
                                                       u16* __restrict__ ctx) {
    __shared__ u16 P[4][32][40];
    int wid = threadIdx.x >> 6, lane = threadIdx.x & 63;
    int g = blockIdx.x * 4 + wid;        // 12288 = H * C * N
    int h = g >> 10;
    int cn = g & 1023;
    int c = cn >> 2, n = cn & 3;
    int li = lane & 15, ko = (lane >> 4) * 8;

    size_t pb = (size_t)(h * 4 + n) * PL_;

    // ---- scores S[i][j] over rows i,j in [0,32), K = d = 64 ----
    f32x4 s[2][2] = {};
#pragma unroll
    for (int d0 = 0; d0 < 64; d0 += 32) {
        short8 aq[2], ak[2];
#pragma unroll
        for (int ia = 0; ia < 2; ia++) {
            size_t oq = pb + ((size_t)((ia * 16 + li) * C_ + c)) * 64 + d0 + ko;
            aq[ia] = *reinterpret_cast<const short8*>(q + oq);
            ak[ia] = *reinterpret_cast<const short8*>(k + oq);
        }
#pragma unroll
        for (int ia = 0; ia < 2; ia++)
#pragma unroll
            for (int jb = 0; jb < 2; jb++)
                s[ia][jb] = __builtin_amdgcn_mfma_f32_16x16x32_bf16(aq[ia], ak[jb], s[ia][jb], 0, 0, 0);
    }
    // ---- softmax over j (32 values per row i) ----
#pragma unroll
    for (int ia = 0; ia < 2; ia++)
#pragma unroll
        for (int rr = 0; rr < 4; rr++) {
            float a0 = s[ia][0][rr] * 0.125f;
            float a1 = s[ia][1][rr] * 0.125f;
            float m = fmaxf(a0, a1);
#pragma unroll
            for (int off = 8; off >= 1; off >>= 1) m = fmaxf(m, __shfl_xor(m, off));
            float e0 = expf(a0 - m), e1 = expf(a1 - m);
            float ss = e0 + e1;
#pragma unroll
            for (int off = 8; off >= 1; off >>= 1) ss += __shfl_xor(ss, off);
            float inv = 1.0f / ss;
            s[ia][0][rr] = e0 * inv;
            s[ia][1][rr] = e1 * inv;
        }
    // ---- P -> LDS (C/D layout -> row-major) ----
#pragma unroll
    for (int ia = 0; ia < 2; ia++)
#pragma unroll
        for (int jb = 0; jb < 2; jb++)
#pragma unroll
            for (int rr = 0; rr < 4; rr++)
                P[wid][ia * 16 + (lane >> 4) * 4 + rr][jb * 16 + li] = f2bf(s[ia][jb][rr]);
    __syncthreads();
    // ---- PV: ctx[i][d] = sum_j P[i][j] * v[j][d] ----
    short8 pa[2];
    pa[0] = *reinterpret_cast<const short8*>(&P[wid][li][ko]);
    pa[1] = *reinterpret_cast<const short8*>(&P[wid][16 + li][ko]);
    f32x4 o[2][4] = {};
#pragma unroll
    for (int df = 0; df < 4; df++) {
        U8 vb;
#pragma unroll
        for (int jj = 0; jj < 8; jj++) {
            int j = (lane >> 4) * 8 + jj;
            vb.u[jj] = v[pb + ((size_t)(j * C_ + c)) * 64 + df * 16 + li];
        }
#pragma unroll
        for (int ia = 0; ia < 2; ia++)
            o[ia][df] = __builtin_amdgcn_mfma_f32_16x16x32_bf16(pa[ia], vb.v, o[ia][df], 0, 0, 0);
    }
#pragma unroll
    for (int ia = 0; ia < 2; ia++)
#pragma unroll
        for (int df = 0; df < 4; df++)
#pragma unroll
            for (int rr = 0; rr < 4; rr++) {
                int i = ia * 16 + (lane >> 4) * 4 + rr;
                int d = df * 16 + li;
                ctx[((size_t)((i * C_ + c) * N_ + n)) * E_ + h * 64 + d] = f2bf(o[ia][df][rr]);
            }
}

// ---------------- launch ----------------
extern "C" void kernel_launch(void* const* d_in, const int* in_sizes, int n_in,
                              void* d_out, int out_size, void* d_ws, size_t ws_size,
                              hipStream_t stream) {
    const float* x     = (const float*)d_in[0];
    const float* ln_w  = (const float*)d_in[1];
    const float* ln_b  = (const float*)d_in[2];
    const float* row_w = (const float*)d_in[3];
    const float* row_b = (const float*)d_in[4];
    const float* col_w = (const float*)d_in[5];
    const float* col_b = (const float*)d_in[6];
    const float* fc1_w = (const float*)d_in[7];
    const float* fc1_b = (const float*)d_in[8];
    const float* fc2_w = (const float*)d_in[9];
    const float* fc2_b = (const float*)d_in[10];
    float* out = (float*)d_out;

    u16* q_bf = (u16*)d_ws;                   // planar [48][32][256][64]
    u16* k_bf = q_bf + TE_;
    u16* v_bf = k_bf + TE_;
    u16* h_bf = v_bf + TE_;                   // token-major; also ctx
    float* aw = (float*)(h_bf + TE_);         // 48*256*256 fp32
    u16* wrow = (u16*)(aw + (size_t)48 * C_ * C_);
    u16* wcol = wrow + (size_t)4 * E_ * E_;
    u16* wfc1 = wcol + (size_t)4 * E_ * E_;
    u16* wfc2 = wfc1 + (size_t)F_ * E_;
    u16* hid = q_bf;                          // [T][1536] aliases q..k

    const int nW = 4 * E_ * E_;               // 2359296
    cvt_kernel<<<nW / 1024, 256, 0, stream>>>(row_w, wrow, nW);
    cvt_kernel<<<nW / 1024, 256, 0, stream>>>(col_w, wcol, nW);
    cvt_kernel<<<nW / 1024, 256, 0, stream>>>(fc1_w, wfc1, nW);
    cvt_kernel<<<nW / 1024, 256, 0, stream>>>(fc2_w, wfc2, nW);

    // grids: 128 m-tiles x nt_n n-tiles
    const int gQKV = 128 * 9;   // N=2304
    const int gOUT = 128 * 3;   // N=768
    const int gFC1 = 128 * 6;   // N=1536
    const int gFC2 = 128 * 3;   // N=768, K=1536

    // ======== Row self-attention block ========
    ln_kernel<<<T_ / 4, 256, 0, stream>>>(x, ln_w, ln_b, h_bf);
    gemm256p<2, false, 12><<<gQKV, 512, 0, stream>>>(h_bf, E_, wrow, E_, row_b, q_bf, E_, nullptr, nullptr, 9);
    row_scores_kernel<<<dim3(16, 48), 256, 0, stream>>>(q_bf, k_bf, aw);
    softmax256_kernel<<<48 * C_ / 4, 256, 0, stream>>>(aw);
    row_ctx_kernel<<<dim3(4, 32, 48), 256, 0, stream>>>(aw, v_bf, h_bf);
    gemm256p<1, false, 12><<<gOUT, 512, 0, stream>>>(h_bf, E_, wrow + (size_t)3 * E_ * E_, E_, row_b + 3 * E_, nullptr, E_, out, x, 3);

    // ======== Column self-attention block ========
    ln_kernel<<<T_ / 4, 256, 0, stream>>>(out, ln_w + E_, ln_b + E_, h_bf);
    gemm256p<2, false, 12><<<gQKV, 512, 0, stream>>>(h_bf, E_, wcol, E_, col_b, q_bf, E_, nullptr, nullptr, 9);
    col_attn_kernel<<<(H_ * C_ * N_) / 4, 256, 0, stream>>>(q_bf, k_bf, v_bf, h_bf);
    gemm256p<1, false, 12><<<gOUT, 512, 0, stream>>>(h_bf, E_, wcol + (size_t)3 * E_ * E_, E_, col_b + 3 * E_, nullptr, E_, out, out, 3);

    // ======== FFN block (two K/N=1536 halves; hidden aliases q..k) ========
    ln_kernel<<<T_ / 4, 256, 0, stream>>>(out, ln_w + 2 * E_, ln_b + 2 * E_, h_bf);
    gemm256p<0, true, 12><<<gFC1, 512, 0, stream>>>(h_bf, E_, wfc1, E_, fc1_b, hid, 1536, nullptr, nullptr, 6);
    gemm256p<1, false, 24><<<gFC2, 512, 0, stream>>>(hid, 1536, wfc2, F_, fc2_b, nullptr, E_, out, out, 3);
    gemm256p<0, true, 12><<<gFC1, 512, 0, stream>>>(h_bf, E_, wfc1 + (size_t)1536 * E_, E_, fc1_b + 1536, hid, 1536, nullptr, nullptr, 6);
    gemm256p<1, false, 24><<<gFC2, 512, 0, stream>>>(hid, 1536, wfc2 + 1536, F_, nullptr, nullptr, E_, out, out, 3);
}

// Round 7
// 1204.723 us; speedup vs baseline: 1.5913x; 1.0347x over previous
//
#include <hip/hip_runtime.h>
#include <hip/hip_bf16.h>
#include <math.h>

typedef unsigned short u16;
typedef __attribute__((ext_vector_type(8))) short short8;
typedef __attribute__((ext_vector_type(4))) float f32x4;

#define E_ 768
#define H_ 12
#define D_ 64
#define C_ 256
#define R_ 32
#define N_ 4
#define F_ 3072
#define T_ 32768   // R_*C_*N_
#define TE_ ((size_t)T_ * E_)
#define PL_ ((size_t)R_ * C_ * 64)   // one (h,n) plane of q/k/v

union U8 { u16 u[8]; short8 v; };

__device__ __forceinline__ u16 f2bf(float f) {
    unsigned u = __builtin_bit_cast(unsigned, f);
    u = (u + 0x7FFFu + ((u >> 16) & 1u)) >> 16;
    return (u16)u;
}
__device__ __forceinline__ float bf2f(u16 h) {
    unsigned u = ((unsigned)h) << 16;
    return __builtin_bit_cast(float, u);
}

__device__ __forceinline__ void gload_lds16(const u16* g, u16* l) {
    __builtin_amdgcn_global_load_lds((const __attribute__((address_space(1))) void*)g,
                                     (__attribute__((address_space(3))) void*)l, 16, 0, 0);
}

// ---------------- fp32 -> bf16 weight convert ----------------
__global__ __launch_bounds__(256) void cvt_kernel(const float* __restrict__ src,
                                                  u16* __restrict__ dst, int n) {
    int i = (blockIdx.x * 256 + threadIdx.x) * 4;
    if (i >= n) return;
    float4 v = *reinterpret_cast<const float4*>(src + i);
    ushort4 o;
    o.x = f2bf(v.x); o.y = f2bf(v.y); o.z = f2bf(v.z); o.w = f2bf(v.w);
    *reinterpret_cast<ushort4*>(dst + i) = o;
}

// ---------------- LayerNorm: one wave per token (E=768) ----------------
__global__ __launch_bounds__(256) void ln_kernel(const float* __restrict__ x,
                                                 const float* __restrict__ w,
                                                 const float* __restrict__ b,
                                                 u16* __restrict__ out) {
    int wid = threadIdx.x >> 6, lane = threadIdx.x & 63;
    size_t t = (size_t)blockIdx.x * 4 + wid;
    const float* xp = x + t * E_;
    float4 v[3];
    float s1 = 0.f, s2 = 0.f;
#pragma unroll
    for (int c = 0; c < 3; c++) {
        v[c] = *reinterpret_cast<const float4*>(xp + c * 256 + lane * 4);
        s1 += v[c].x + v[c].y + v[c].z + v[c].w;
        s2 += v[c].x * v[c].x + v[c].y * v[c].y + v[c].z * v[c].z + v[c].w * v[c].w;
    }
#pragma unroll
    for (int off = 32; off >= 1; off >>= 1) {
        s1 += __shfl_xor(s1, off);
        s2 += __shfl_xor(s2, off);
    }
    float mu = s1 * (1.0f / E_);
    float var = s2 * (1.0f / E_) - mu * mu;
    float inv = rsqrtf(var + 1e-12f);
#pragma unroll
    for (int c = 0; c < 3; c++) {
        int e = c * 256 + lane * 4;
        float4 wv = *reinterpret_cast<const float4*>(w + e);
        float4 bv = *reinterpret_cast<const float4*>(b + e);
        ushort4 o;
        o.x = f2bf((v[c].x - mu) * inv * wv.x + bv.x);
        o.y = f2bf((v[c].y - mu) * inv * wv.y + bv.y);
        o.z = f2bf((v[c].z - mu) * inv * wv.z + bv.z);
        o.w = f2bf((v[c].w - mu) * inv * wv.w + bv.w);
        *reinterpret_cast<ushort4*>(out + t * E_ + e) = o;
    }
}

// ===== 128x128 GEMM, BK=32, double-buffered, 4 blocks/CU (m97-TLP + T2+T4) =====
// 256 thr / 4 waves (2m x 2n), wave tile 64x64. LDS 32 KB:
//   A buf b @ u16 b*4096 (64 lines x 128 B; line p = rows 2p,2p+1),
//   B buf b @ u16 8192 + b*4096.
// Byte-in-line XOR-swizzle ^((line&7)<<4); staging source pre-inverse-swizzled
// (verified: thread tid=9/13 land rows 2/3 chunk0 where reads expect them).
// Loop: {ds_read 8 frags | lgkmcnt(0) | barrier | stage(t+2) into same buf |
//        16 MFMA (setprio) | vmcnt(4) | barrier}  -- counted vmcnt: next tile's
// 4 loads stay in flight across the boundary; 4 independent blocks/CU hide
// the rest (1-block 256^2 design was barrier-stall-bound at 30% MfmaUtil).
// MODE 0: bf16 store (opt GELU). 1: fp32 resid add. 2: qkv planar split.
template<int MODE, bool GELU, int NT>
__global__ __launch_bounds__(256, 4) void gemm128d(
    const u16* __restrict__ A, int lda,
    const u16* __restrict__ W, int ldw,
    const float* __restrict__ bias,
    u16* __restrict__ dstB, int ldd,
    float* __restrict__ dstF, const float* __restrict__ resid,
    int nt_n) {
    static_assert(NT >= 3, "need >=3 K-tiles");
    __shared__ u16 lds[16384];   // 32 KB
    const int tid = threadIdx.x;
    const int w4 = tid >> 6, lane = tid & 63;
    const int wm = w4 >> 1, wn = w4 & 1;
    const int li = lane & 15, hi = lane >> 4;

    // T1: XCD-contiguous swizzle + supergroups of 8 m-tiles (n-inner)
    int nwg = gridDim.x;
    int cpx = nwg >> 3;
    int lbid = (blockIdx.x & 7) * cpx + (blockIdx.x >> 3);
    int sgsz = nt_n << 3;
    int sg = lbid / sgsz, rem = lbid - sg * sgsz;
    int nt = rem >> 3, mt = (sg << 3) + (rem & 7);
    int m0 = mt << 7, n0 = nt << 7;

    // staging source (inverse swizzle)
    const int t7 = ((tid & 7) * 16) ^ (((tid >> 3) & 7) << 4);
    const int rloc = ((tid >> 3) << 1) | (t7 >> 6);   // 0..63
    const int cel = (t7 & 63) >> 1;                   // 0..31 u16
    const u16* gA0 = A + (size_t)(m0 + rloc) * lda + cel;
    const u16* gA1 = A + (size_t)(m0 + 64 + rloc) * lda + cel;
    const u16* gB0 = W + (size_t)(n0 + rloc) * ldw + cel;
    const u16* gB1 = W + (size_t)(n0 + 64 + rloc) * ldw + cel;
    const int dst8 = tid * 8;   // u16: 16 B per thread per inst (4 KB/inst)

    // frag read offsets (u16) inside an operand buf
    const int colx = (((li & 1) * 64) | (hi * 16)) ^ ((li >> 1) << 4);
    const int aOff = ((wm * 32 + (li >> 1)) * 128 + colx) >> 1;
    const int bOff = ((wn * 32 + (li >> 1)) * 128 + colx) >> 1;

    short8 af[4], bfr[4];
    f32x4 acc[4][4] = {};

#define STG(t) { int b_ = ((t) & 1) * 4096; int ko_ = (t) * 32;          \
        gload_lds16(gA0 + ko_, lds + b_ + dst8);                         \
        gload_lds16(gA1 + ko_, lds + b_ + 2048 + dst8);                  \
        gload_lds16(gB0 + ko_, lds + 8192 + b_ + dst8);                  \
        gload_lds16(gB1 + ko_, lds + 8192 + b_ + 2048 + dst8); }

#define RDS(t) { int b_ = ((t) & 1) * 4096;                              \
        const u16* pa_ = lds + b_ + aOff;                                \
        const u16* pb_ = lds + 8192 + b_ + bOff;                         \
        _Pragma("unroll") for (int f = 0; f < 4; f++) {                  \
            af[f]  = *reinterpret_cast<const short8*>(pa_ + f * 512);    \
            bfr[f] = *reinterpret_cast<const short8*>(pb_ + f * 512); } }

#define MM() { __builtin_amdgcn_s_setprio(1);                            \
        _Pragma("unroll") for (int mf = 0; mf < 4; mf++)                 \
        _Pragma("unroll") for (int nf = 0; nf < 4; nf++)                 \
            acc[mf][nf] = __builtin_amdgcn_mfma_f32_16x16x32_bf16(       \
                af[mf], bfr[nf], acc[mf][nf], 0, 0, 0);                  \
        __builtin_amdgcn_s_setprio(0); }

#define BARR() { asm volatile("" ::: "memory");                          \
                 __builtin_amdgcn_s_barrier();                           \
                 asm volatile("" ::: "memory"); }
#define LGK0() asm volatile("s_waitcnt lgkmcnt(0)" ::: "memory")
#define VMW4() asm volatile("s_waitcnt vmcnt(4)" ::: "memory")
#define VMW0() asm volatile("s_waitcnt vmcnt(0)" ::: "memory")

    // prologue: stage tiles 0 and 1
    STG(0); STG(1);
    VMW4(); BARR();                 // tile 0 landed; tile 1 in flight

#pragma unroll 1
    for (int t = 0; t < NT - 2; ++t) {
        RDS(t); LGK0(); BARR();     // all waves consumed buf t&1
        STG(t + 2);                 // refill it (t+2); t+1 still in flight
        MM();
        VMW4(); BARR();             // t+1 landed; t+2 in flight
    }
    RDS(NT - 2); LGK0(); MM();
    VMW0(); BARR();                 // last tile landed
    RDS(NT - 1); LGK0(); MM();

#undef STG
#undef RDS
#undef MM
#undef BARR
#undef LGK0
#undef VMW4
#undef VMW0

    // ---- epilogue ----
#pragma unroll
    for (int mf = 0; mf < 4; mf++)
#pragma unroll
        for (int nf = 0; nf < 4; nf++) {
            int n = n0 + wn * 64 + nf * 16 + li;
            float bn = bias ? bias[n] : 0.0f;
#pragma unroll
            for (int r = 0; r < 4; r++) {
                int m = m0 + wm * 64 + mf * 16 + hi * 4 + r;
                float vv = acc[mf][nf][r] + bn;
                if (GELU) vv = 0.5f * vv * (1.0f + erff(vv * 0.70710678118654752f));
                if (MODE == 0) {
                    dstB[(size_t)m * ldd + n] = f2bf(vv);
                } else if (MODE == 1) {
                    dstF[(size_t)m * E_ + n] = resid[(size_t)m * E_ + n] + vv;
                } else {
                    int third = (n >= 1536) ? 2 : ((n >= 768) ? 1 : 0);
                    int rem2 = n - third * 768;
                    int hh = rem2 >> 6, dd = rem2 & 63;
                    int ntok = m & 3, cc = (m >> 2) & 255, rr = m >> 10;
                    dstB[(size_t)third * TE_ +
                         (((size_t)(hh * 4 + ntok) * R_ + rr) * C_ + cc) * 64 + dd] = f2bf(vv);
                }
            }
        }
}

// ---- Row-attention scores (planar q/k): aw[hn,i,j] = s * sum_{r,d} q·k ----
__global__ __launch_bounds__(256) void row_scores_kernel(const u16* __restrict__ q,
                                                         const u16* __restrict__ k,
                                                         float* __restrict__ aw) {
    int tile = blockIdx.x;            // 16: 4 i-tiles x 4 j-tiles
    int hn = blockIdx.y;              // 48
    int i0 = (tile >> 2) * 64, j0 = (tile & 3) * 64;
    int wid = threadIdx.x >> 6, lane = threadIdx.x & 63;
    int wy = wid >> 1, wx = wid & 1;
    int iW = i0 + wy * 32, jW = j0 + wx * 32;
    int li = lane & 15, ko = (lane >> 4) * 8;

    const u16* qp = q + (size_t)hn * PL_;
    const u16* kp = k + (size_t)hn * PL_;

    f32x4 acc[2][2] = {};
    for (int r = 0; r < R_; r++) {
#pragma unroll
        for (int d0 = 0; d0 < 64; d0 += 32) {
            short8 aq[2], ak[2];
#pragma unroll
            for (int mi = 0; mi < 2; mi++) {
                aq[mi] = *reinterpret_cast<const short8*>(qp + ((size_t)(r * C_ + iW + mi * 16 + li)) * 64 + d0 + ko);
                ak[mi] = *reinterpret_cast<const short8*>(kp + ((size_t)(r * C_ + jW + mi * 16 + li)) * 64 + d0 + ko);
            }
#pragma unroll
            for (int mi = 0; mi < 2; mi++)
#pragma unroll
                for (int ni = 0; ni < 2; ni++)
                    acc[mi][ni] = __builtin_amdgcn_mfma_f32_16x16x32_bf16(aq[mi], ak[ni], acc[mi][ni], 0, 0, 0);
        }
    }
    const float scale = 0.02209708691207961f;  // (1/8) / sqrt(32)
#pragma unroll
    for (int mi = 0; mi < 2; mi++)
#pragma unroll
        for (int ni = 0; ni < 2; ni++)
#pragma unroll
            for (int r = 0; r < 4; r++) {
                int i = iW + mi * 16 + (lane >> 4) * 4 + r;
                int j = jW + ni * 16 + li;
                aw[((size_t)hn * C_ + i) * C_ + j] = acc[mi][ni][r] * scale;
            }
}

// ---------------- softmax over rows of length 256, in place ----------------
__global__ __launch_bounds__(256) void softmax256_kernel(float* __restrict__ aw) {
    int wid = threadIdx.x >> 6, lane = threadIdx.x & 63;
    size_t row = (size_t)blockIdx.x * 4 + wid;
    float* p = aw + row * 256;
    float4 v = reinterpret_cast<float4*>(p)[lane];
    float m = fmaxf(fmaxf(v.x, v.y), fmaxf(v.z, v.w));
#pragma unroll
    for (int off = 32; off >= 1; off >>= 1) m = fmaxf(m, __shfl_xor(m, off));
    float e0 = expf(v.x - m), e1 = expf(v.y - m), e2 = expf(v.z - m), e3 = expf(v.w - m);
    float s = e0 + e1 + e2 + e3;
#pragma unroll
    for (int off = 32; off >= 1; off >>= 1) s += __shfl_xor(s, off);
    float inv = 1.0f / s;
    float4 o; o.x = e0 * inv; o.y = e1 * inv; o.z = e2 * inv; o.w = e3 * inv;
    reinterpret_cast<float4*>(p)[lane] = o;
}

// ---- Row-attention AP·V (planar v): ctx[r,i,n,h,d] token-major out ----
__global__ __launch_bounds__(256) void row_ctx_kernel(const float* __restrict__ ap,
                                                      const u16* __restrict__ v,
                                                      u16* __restrict__ ctx) {
    int i0 = blockIdx.x * 64;     // 4 tiles
    int r = blockIdx.y;           // 32
    int hn = blockIdx.z;          // 48
    int h = hn >> 2, n = hn & 3;
    __shared__ u16 APs[64][40];
    __shared__ u16 Vts[64][40];   // Vt[d][j]
    int tid = threadIdx.x, wid = tid >> 6, lane = tid & 63;
    int wy = wid >> 1, wx = wid & 1;
    int li = lane & 15, ko = (lane >> 4) * 8;
    int ai = tid >> 2, aj = (tid & 3) * 8;   // AP staging: [64 i][32 j]
    int vj = tid >> 3, vd = (tid & 7) * 8;   // V staging: 32 j rows, 8 d each

    const u16* vp = v + (size_t)hn * PL_;

    f32x4 acc[2][2] = {};
    for (int j0 = 0; j0 < C_; j0 += 32) {
        const float* aps = ap + ((size_t)hn * C_ + i0 + ai) * C_ + j0 + aj;
        float4 p0 = *reinterpret_cast<const float4*>(aps);
        float4 p1 = *reinterpret_cast<const float4*>(aps + 4);
        U8 t8;
        t8.u[0] = f2bf(p0.x); t8.u[1] = f2bf(p0.y); t8.u[2] = f2bf(p0.z); t8.u[3] = f2bf(p0.w);
        t8.u[4] = f2bf(p1.x); t8.u[5] = f2bf(p1.y); t8.u[6] = f2bf(p1.z); t8.u[7] = f2bf(p1.w);
        *reinterpret_cast<short8*>(&APs[ai][aj]) = t8.v;
        U8 vv;
        vv.v = *reinterpret_cast<const short8*>(vp + ((size_t)(r * C_ + j0 + vj)) * 64 + vd);
#pragma unroll
        for (int u = 0; u < 8; u++) Vts[vd + u][vj] = vv.u[u];
        __syncthreads();
        short8 af[2], vf[2];
        af[0] = *reinterpret_cast<const short8*>(&APs[wy * 32 + li][ko]);
        af[1] = *reinterpret_cast<const short8*>(&APs[wy * 32 + 16 + li][ko]);
        vf[0] = *reinterpret_cast<const short8*>(&Vts[wx * 32 + li][ko]);
        vf[1] = *reinterpret_cast<const short8*>(&Vts[wx * 32 + 16 + li][ko]);
#pragma unroll
        for (int mi = 0; mi < 2; mi++)
#pragma unroll
            for (int ni = 0; ni < 2; ni++)
                acc[mi][ni] = __builtin_amdgcn_mfma_f32_16x16x32_bf16(af[mi], vf[ni], acc[mi][ni], 0, 0, 0);
        __syncthreads();
    }
#pragma unroll
    for (int mi = 0; mi < 2; mi++)
#pragma unroll
        for (int ni = 0; ni < 2; ni++)
#pragma unroll
            for (int rr = 0; rr < 4; rr++) {
                int i = i0 + wy * 32 + mi * 16 + (lane >> 4) * 4 + rr;
                int d = wx * 32 + ni * 16 + li;
                ctx[((size_t)((r * C_ + i) * N_ + n)) * E_ + h * 64 + d] = f2bf(acc[mi][ni][rr]);
            }
}

// ---- Column attention (planar q/k/v), fused: one wave per (h,c,n) ----
__global__ __launch_bounds__(256) void col_attn_kernel(const u16* __restrict__ q,
                                                       const u16* __restrict__ k,
                                                       const u16* __restrict__ v,
                                                       u16* __restrict__ ctx) {
    __shared__ u16 P[4][32][40];
    int wid = threadIdx.x >> 6, lane = threadIdx.x & 63;
    int g = blockIdx.x * 4 + wid;        // 12288 = H * C * N
    int h = g >> 10;
    int cn = g & 1023;
    int c = cn >> 2, n = cn & 3;
    int li = lane & 15, ko = (lane >> 4) * 8;

    size_t pb = (size_t)(h * 4 + n) * PL_;

    // ---- scores S[i][j] over rows i,j in [0,32), K = d = 64 ----
    f32x4 s[2][2] = {};
#pragma unroll
    for (int d0 = 0; d0 < 64; d0 += 32) {
        short8 aq[2], ak[2];
#pragma unroll
        for (int ia = 0; ia < 2; ia++) {
            size_t oq = pb + ((size_t)((ia * 16 + li) * C_ + c)) * 64 + d0 + ko;
            aq[ia] = *reinterpret_cast<const short8*>(q + oq);
            ak[ia] = *reinterpret_cast<const short8*>(k + oq);
        }
#pragma unroll
        for (int ia = 0; ia < 2; ia++)
#pragma unroll
            for (int jb = 0; jb < 2; jb++)
                s[ia][jb] = __builtin_amdgcn_mfma_f32_16x16x32_bf16(aq[ia], ak[jb], s[ia][jb], 0, 0, 0);
    }
    // ---- softmax over j (32 values per row i) ----
#pragma unroll
    for (int ia = 0; ia < 2; ia++)
#pragma unroll
        for (int rr = 0; rr < 4; rr++) {
            float a0 = s[ia][0][rr] * 0.125f;
            float a1 = s[ia][1][rr] * 0.125f;
            float m = fmaxf(a0, a1);
#pragma unroll
            for (int off = 8; off >= 1; off >>= 1) m = fmaxf(m, __shfl_xor(m, off));
            float e0 = expf(a0 - m), e1 = expf(a1 - m);
            float ss = e0 + e1;
#pragma unroll
            for (int off = 8; off >= 1; off >>= 1) ss += __shfl_xor(ss, off);
            float inv = 1.0f / ss;
            s[ia][0][rr] = e0 * inv;
            s[ia][1][rr] = e1 * inv;
        }
    // ---- P -> LDS (C/D layout -> row-major) ----
#pragma unroll
    for (int ia = 0; ia < 2; ia++)
#pragma unroll
        for (int jb = 0; jb < 2; jb++)
#pragma unroll
            for (int rr = 0; rr < 4; rr++)
                P[wid][ia * 16 + (lane >> 4) * 4 + rr][jb * 16 + li] = f2bf(s[ia][jb][rr]);
    __syncthreads();
    // ---- PV: ctx[i][d] = sum_j P[i][j] * v[j][d] ----
    short8 pa[2];
    pa[0] = *reinterpret_cast<const short8*>(&P[wid][li][ko]);
    pa[1] = *reinterpret_cast<const short8*>(&P[wid][16 + li][ko]);
    f32x4 o[2][4] = {};
#pragma unroll
    for (int df = 0; df < 4; df++) {
        U8 vb;
#pragma unroll
        for (int jj = 0; jj < 8; jj++) {
            int j = (lane >> 4) * 8 + jj;
            vb.u[jj] = v[pb + ((size_t)(j * C_ + c)) * 64 + df * 16 + li];
        }
#pragma unroll
        for (int ia = 0; ia < 2; ia++)
            o[ia][df] = __builtin_amdgcn_mfma_f32_16x16x32_bf16(pa[ia], vb.v, o[ia][df], 0, 0, 0);
    }
#pragma unroll
    for (int ia = 0; ia < 2; ia++)
#pragma unroll
        for (int df = 0; df < 4; df++)
#pragma unroll
            for (int rr = 0; rr < 4; rr++) {
                int i = ia * 16 + (lane >> 4) * 4 + rr;
                int d = df * 16 + li;
                ctx[((size_t)((i * C_ + c) * N_ + n)) * E_ + h * 64 + d] = f2bf(o[ia][df][rr]);
            }
}

// ---------------- launch ----------------
extern "C" void kernel_launch(void* const* d_in, const int* in_sizes, int n_in,
                              void* d_out, int out_size, void* d_ws, size_t ws_size,
                              hipStream_t stream) {
    const float* x     = (const float*)d_in[0];
    const float* ln_w  = (const float*)d_in[1];
    const float* ln_b  = (const float*)d_in[2];
    const float* row_w = (const float*)d_in[3];
    const float* row_b = (const float*)d_in[4];
    const float* col_w = (const float*)d_in[5];
    const float* col_b = (const float*)d_in[6];
    const float* fc1_w = (const float*)d_in[7];
    const float* fc1_b = (const float*)d_in[8];
    const float* fc2_w = (const float*)d_in[9];
    const float* fc2_b = (const float*)d_in[10];
    float* out = (float*)d_out;

    u16* q_bf = (u16*)d_ws;                   // planar [48][32][256][64]
    u16* k_bf = q_bf + TE_;
    u16* v_bf = k_bf + TE_;
    u16* h_bf = v_bf + TE_;                   // token-major; also ctx
    float* aw = (float*)(h_bf + TE_);         // 48*256*256 fp32
    u16* wrow = (u16*)(aw + (size_t)48 * C_ * C_);
    u16* wcol = wrow + (size_t)4 * E_ * E_;
    u16* wfc1 = wcol + (size_t)4 * E_ * E_;
    u16* wfc2 = wfc1 + (size_t)F_ * E_;
    u16* hid = q_bf;                          // [T][1536] aliases q..k

    const int nW = 4 * E_ * E_;               // 2359296
    cvt_kernel<<<nW / 1024, 256, 0, stream>>>(row_w, wrow, nW);
    cvt_kernel<<<nW / 1024, 256, 0, stream>>>(col_w, wcol, nW);
    cvt_kernel<<<nW / 1024, 256, 0, stream>>>(fc1_w, wfc1, nW);
    cvt_kernel<<<nW / 1024, 256, 0, stream>>>(fc2_w, wfc2, nW);

    // grids: 256 m-tiles x nt_n n-tiles (128-wide)
    const int gQKV = 256 * 18;   // N=2304
    const int gOUT = 256 * 6;    // N=768
    const int gFC1 = 256 * 12;   // N=1536
    const int gFC2 = 256 * 6;    // N=768, K=1536

    // ======== Row self-attention block ========
    ln_kernel<<<T_ / 4, 256, 0, stream>>>(x, ln_w, ln_b, h_bf);
    gemm128d<2, false, 24><<<gQKV, 256, 0, stream>>>(h_bf, E_, wrow, E_, row_b, q_bf, E_, nullptr, nullptr, 18);
    row_scores_kernel<<<dim3(16, 48), 256, 0, stream>>>(q_bf, k_bf, aw);
    softmax256_kernel<<<48 * C_ / 4, 256, 0, stream>>>(aw);
    row_ctx_kernel<<<dim3(4, 32, 48), 256, 0, stream>>>(aw, v_bf, h_bf);
    gemm128d<1, false, 24><<<gOUT, 256, 0, stream>>>(h_bf, E_, wrow + (size_t)3 * E_ * E_, E_, row_b + 3 * E_, nullptr, E_, out, x, 6);

    // ======== Column self-attention block ========
    ln_kernel<<<T_ / 4, 256, 0, stream>>>(out, ln_w + E_, ln_b + E_, h_bf);
    gemm128d<2, false, 24><<<gQKV, 256, 0, stream>>>(h_bf, E_, wcol, E_, col_b, q_bf, E_, nullptr, nullptr, 18);
    col_attn_kernel<<<(H_ * C_ * N_) / 4, 256, 0, stream>>>(q_bf, k_bf, v_bf, h_bf);
    gemm128d<1, false, 24><<<gOUT, 256, 0, stream>>>(h_bf, E_, wcol + (size_t)3 * E_ * E_, E_, col_b + 3 * E_, nullptr, E_, out, out, 6);

    // ======== FFN block (two K/N=1536 halves; hidden aliases q..k) ========
    ln_kernel<<<T_ / 4, 256, 0, stream>>>(out, ln_w + 2 * E_, ln_b + 2 * E_, h_bf);
    gemm128d<0, true, 24><<<gFC1, 256, 0, stream>>>(h_bf, E_, wfc1, E_, fc1_b, hid, 1536, nullptr, nullptr, 12);
    gemm128d<1, false, 48><<<gFC2, 256, 0, stream>>>(hid, 1536, wfc2, F_, fc2_b, nullptr, E_, out, out, 6);
    gemm128d<0, true, 24><<<gFC1, 256, 0, stream>>>(h_bf, E_, wfc1 + (size_t)1536 * E_, E_, fc1_b + 1536, hid, 1536, nullptr, nullptr, 12);
    gemm128d<1, false, 48><<<gFC2, 256, 0, stream>>>(hid, 1536, wfc2 + 1536, F_, nullptr, nullptr, E_, out, out, 6);
}

// Round 8
// 1171.755 us; speedup vs baseline: 1.6361x; 1.0281x over previous
//
#include <hip/hip_runtime.h>
#include <hip/hip_bf16.h>
#include <math.h>

typedef unsigned short u16;
typedef __attribute__((ext_vector_type(8))) short short8;
typedef __attribute__((ext_vector_type(4))) float f32x4;

#define E_ 768
#define H_ 12
#define D_ 64
#define C_ 256
#define R_ 32
#define N_ 4
#define F_ 3072
#define T_ 32768   // R_*C_*N_
#define TE_ ((size_t)T_ * E_)
#define PL_ ((size_t)R_ * C_ * 64)   // one (h,n) plane of q/k/v

union U8 { u16 u[8]; short8 v; };

__device__ __forceinline__ u16 f2bf(float f) {
    unsigned u = __builtin_bit_cast(unsigned, f);
    u = (u + 0x7FFFu + ((u >> 16) & 1u)) >> 16;
    return (u16)u;
}
__device__ __forceinline__ float bf2f(u16 h) {
    unsigned u = ((unsigned)h) << 16;
    return __builtin_bit_cast(float, u);
}

__device__ __forceinline__ void gload_lds16(const u16* g, u16* l) {
    __builtin_amdgcn_global_load_lds((const __attribute__((address_space(1))) void*)g,
                                     (__attribute__((address_space(3))) void*)l, 16, 0, 0);
}

// ---------------- fp32 -> bf16 weight convert ----------------
__global__ __launch_bounds__(256) void cvt_kernel(const float* __restrict__ src,
                                                  u16* __restrict__ dst, int n) {
    int i = (blockIdx.x * 256 + threadIdx.x) * 4;
    if (i >= n) return;
    float4 v = *reinterpret_cast<const float4*>(src + i);
    ushort4 o;
    o.x = f2bf(v.x); o.y = f2bf(v.y); o.z = f2bf(v.z); o.w = f2bf(v.w);
    *reinterpret_cast<ushort4*>(dst + i) = o;
}

// ---------------- LayerNorm: one wave per token (E=768) ----------------
__global__ __launch_bounds__(256) void ln_kernel(const float* __restrict__ x,
                                                 const float* __restrict__ w,
                                                 const float* __restrict__ b,
                                                 u16* __restrict__ out) {
    int wid = threadIdx.x >> 6, lane = threadIdx.x & 63;
    size_t t = (size_t)blockIdx.x * 4 + wid;
    const float* xp = x + t * E_;
    float4 v[3];
    float s1 = 0.f, s2 = 0.f;
#pragma unroll
    for (int c = 0; c < 3; c++) {
        v[c] = *reinterpret_cast<const float4*>(xp + c * 256 + lane * 4);
        s1 += v[c].x + v[c].y + v[c].z + v[c].w;
        s2 += v[c].x * v[c].x + v[c].y * v[c].y + v[c].z * v[c].z + v[c].w * v[c].w;
    }
#pragma unroll
    for (int off = 32; off >= 1; off >>= 1) {
        s1 += __shfl_xor(s1, off);
        s2 += __shfl_xor(s2, off);
    }
    float mu = s1 * (1.0f / E_);
    float var = s2 * (1.0f / E_) - mu * mu;
    float inv = rsqrtf(var + 1e-12f);
#pragma unroll
    for (int c = 0; c < 3; c++) {
        int e = c * 256 + lane * 4;
        float4 wv = *reinterpret_cast<const float4*>(w + e);
        float4 bv = *reinterpret_cast<const float4*>(b + e);
        ushort4 o;
        o.x = f2bf((v[c].x - mu) * inv * wv.x + bv.x);
        o.y = f2bf((v[c].y - mu) * inv * wv.y + bv.y);
        o.z = f2bf((v[c].z - mu) * inv * wv.z + bv.z);
        o.w = f2bf((v[c].w - mu) * inv * wv.w + bv.w);
        *reinterpret_cast<ushort4*>(out + t * E_ + e) = o;
    }
}

// ===== 256x128 GEMM, BK=32, TRIPLE-buffered, 1 barrier/K-step, 2 blk/CU =====
// 512 thr / 8 waves (4m x 2n), wave tile 64x64. LDS 72 KB:
//   A buf b (16KB, 256 rows) @ u16 b*8192 ; B buf b (8KB, 128 rows) @ 24576+b*4096.
// Rows packed 2/128B-line; byte-in-line XOR-swizzle ^((line&7)<<4) (0-conflict,
// validated R3-R7); staging sources pre-inverse-swizzled.
// 3 buffers => STG(t+2) never touches the buffer being read this iter, and the
// buffer it overwrites ((t-1)%3) was retired at the PREVIOUS end-of-iter
// barrier => only ONE barrier per K-step (R7 had 2; barrier stalls dominated).
// Counted vmcnt(3): tile t+1's 3 loads land, t+2's stay in flight (~2 iters of
// latency slack). 2 blocks/CU (72KB LDS, <=128 VGPR via launch_bounds(512,4)).
// MODE 0: bf16 store (opt GELU). 1: fp32 resid add. 2: qkv planar split.
template<int MODE, bool GELU, int NT>
__global__ __launch_bounds__(512, 4) void gemmP(
    const u16* __restrict__ A, int lda,
    const u16* __restrict__ W, int ldw,
    const float* __restrict__ bias,
    u16* __restrict__ dstB, int ldd,
    float* __restrict__ dstF, const float* __restrict__ resid,
    int nt_n) {
    static_assert(NT >= 3, "need >=3 K-tiles");
    __shared__ u16 lds[36864];   // 72 KB
    const int tid = threadIdx.x;
    const int w8 = tid >> 6, lane = tid & 63;
    const int wm = w8 >> 1, wn = w8 & 1;
    const int li = lane & 15, hi = lane >> 4;

    // T1: XCD-contiguous swizzle + supergroups of 8 m-tiles (n-inner)
    int nwg = gridDim.x;
    int cpx = nwg >> 3;
    int lbid = (blockIdx.x & 7) * cpx + (blockIdx.x >> 3);
    int sgsz = nt_n << 3;
    int sg = lbid / sgsz, rem = lbid - sg * sgsz;
    int nt = rem >> 3, mt = (sg << 3) + (rem & 7);
    int m0 = mt << 8, n0 = nt << 7;

    // staging source (inverse swizzle)
    const int t7 = ((tid & 7) * 16) ^ (((tid >> 3) & 7) << 4);
    const int rloc = ((tid >> 3) << 1) | (t7 >> 6);   // 0..127
    const int cel = (t7 & 63) >> 1;                   // 0..31 u16
    const u16* gA0 = A + (size_t)(m0 + rloc) * lda + cel;
    const u16* gA1 = A + (size_t)(m0 + 128 + rloc) * lda + cel;
    const u16* gB0 = W + (size_t)(n0 + rloc) * ldw + cel;
    const int dst8 = tid * 8;   // u16: 16 B per thread per inst (8 KB/inst)

    // frag read offsets (u16) inside operand bufs
    const int colx = (((li & 1) * 64) | (hi * 16)) ^ ((li >> 1) << 4);
    const int aOff = ((wm * 32 + (li >> 1)) * 128 + colx) >> 1;
    const int bOff = ((wn * 32 + (li >> 1)) * 128 + colx) >> 1;

    short8 af[4], bfr[4];
    f32x4 acc[4][4] = {};

#define STG(t) { int b_ = ((t) % 3); int ko_ = (t) * 32;                 \
        gload_lds16(gA0 + ko_, lds + b_ * 8192 + dst8);                  \
        gload_lds16(gA1 + ko_, lds + b_ * 8192 + 4096 + dst8);           \
        gload_lds16(gB0 + ko_, lds + 24576 + b_ * 4096 + dst8); }

#define RDS(t) { int b_ = ((t) % 3);                                     \
        const u16* pa_ = lds + b_ * 8192 + aOff;                         \
        const u16* pb_ = lds + 24576 + b_ * 4096 + bOff;                 \
        _Pragma("unroll") for (int f = 0; f < 4; f++) {                  \
            af[f]  = *reinterpret_cast<const short8*>(pa_ + f * 512);    \
            bfr[f] = *reinterpret_cast<const short8*>(pb_ + f * 512); } }

#define MM() { __builtin_amdgcn_s_setprio(1);                            \
        _Pragma("unroll") for (int mf = 0; mf < 4; mf++)                 \
        _Pragma("unroll") for (int nf = 0; nf < 4; nf++)                 \
            acc[mf][nf] = __builtin_amdgcn_mfma_f32_16x16x32_bf16(       \
                af[mf], bfr[nf], acc[mf][nf], 0, 0, 0);                  \
        __builtin_amdgcn_s_setprio(0); }

#define BARR() { asm volatile("" ::: "memory");                          \
                 __builtin_amdgcn_s_barrier();                           \
                 asm volatile("" ::: "memory"); }
#define LGK0() asm volatile("s_waitcnt lgkmcnt(0)" ::: "memory")
#define VMW3() asm volatile("s_waitcnt vmcnt(3)" ::: "memory")
#define VMW0() asm volatile("s_waitcnt vmcnt(0)" ::: "memory")

    // prologue: stage tiles 0,1
    STG(0); STG(1);
    VMW3(); BARR();                 // tile 0 landed (all waves); tile 1 in flight

#pragma unroll 1
    for (int t = 0; t < NT - 2; ++t) {
        RDS(t); LGK0();             // frags of tile t in regs
        STG(t + 2);                 // buf (t+2)%3 == (t-1)%3: retired at prev barrier
        MM();
        VMW3(); BARR();             // t+1 landed collectively; t+2 in flight
    }
    RDS(NT - 2); LGK0(); MM();
    VMW0(); BARR();                 // tile NT-1 landed
    RDS(NT - 1); LGK0(); MM();

#undef STG
#undef RDS
#undef MM
#undef BARR
#undef LGK0
#undef VMW3
#undef VMW0

    // ---- epilogue ----
#pragma unroll
    for (int mf = 0; mf < 4; mf++)
#pragma unroll
        for (int nf = 0; nf < 4; nf++) {
            int n = n0 + wn * 64 + nf * 16 + li;
            float bn = bias ? bias[n] : 0.0f;
#pragma unroll
            for (int r = 0; r < 4; r++) {
                int m = m0 + wm * 64 + mf * 16 + hi * 4 + r;
                float vv = acc[mf][nf][r] + bn;
                if (GELU) vv = 0.5f * vv * (1.0f + erff(vv * 0.70710678118654752f));
                if (MODE == 0) {
                    dstB[(size_t)m * ldd + n] = f2bf(vv);
                } else if (MODE == 1) {
                    dstF[(size_t)m * E_ + n] = resid[(size_t)m * E_ + n] + vv;
                } else {
                    int third = (n >= 1536) ? 2 : ((n >= 768) ? 1 : 0);
                    int rem2 = n - third * 768;
                    int hh = rem2 >> 6, dd = rem2 & 63;
                    int ntok = m & 3, cc = (m >> 2) & 255, rr = m >> 10;
                    dstB[(size_t)third * TE_ +
                         (((size_t)(hh * 4 + ntok) * R_ + rr) * C_ + cc) * 64 + dd] = f2bf(vv);
                }
            }
        }
}

// ---- Row-attention scores (planar q/k): aw[hn,i,j] = s * sum_{r,d} q·k ----
__global__ __launch_bounds__(256) void row_scores_kernel(const u16* __restrict__ q,
                                                         const u16* __restrict__ k,
                                                         float* __restrict__ aw) {
    int tile = blockIdx.x;            // 16: 4 i-tiles x 4 j-tiles
    int hn = blockIdx.y;              // 48
    int i0 = (tile >> 2) * 64, j0 = (tile & 3) * 64;
    int wid = threadIdx.x >> 6, lane = threadIdx.x & 63;
    int wy = wid >> 1, wx = wid & 1;
    int iW = i0 + wy * 32, jW = j0 + wx * 32;
    int li = lane & 15, ko = (lane >> 4) * 8;

    const u16* qp = q + (size_t)hn * PL_;
    const u16* kp = k + (size_t)hn * PL_;

    f32x4 acc[2][2] = {};
    for (int r = 0; r < R_; r++) {
#pragma unroll
        for (int d0 = 0; d0 < 64; d0 += 32) {
            short8 aq[2], ak[2];
#pragma unroll
            for (int mi = 0; mi < 2; mi++) {
                aq[mi] = *reinterpret_cast<const short8*>(qp + ((size_t)(r * C_ + iW + mi * 16 + li)) * 64 + d0 + ko);
                ak[mi] = *reinterpret_cast<const short8*>(kp + ((size_t)(r * C_ + jW + mi * 16 + li)) * 64 + d0 + ko);
            }
#pragma unroll
            for (int mi = 0; mi < 2; mi++)
#pragma unroll
                for (int ni = 0; ni < 2; ni++)
                    acc[mi][ni] = __builtin_amdgcn_mfma_f32_16x16x32_bf16(aq[mi], ak[ni], acc[mi][ni], 0, 0, 0);
        }
    }
    const float scale = 0.02209708691207961f;  // (1/8) / sqrt(32)
#pragma unroll
    for (int mi = 0; mi < 2; mi++)
#pragma unroll
        for (int ni = 0; ni < 2; ni++)
#pragma unroll
            for (int r = 0; r < 4; r++) {
                int i = iW + mi * 16 + (lane >> 4) * 4 + r;
                int j = jW + ni * 16 + li;
                aw[((size_t)hn * C_ + i) * C_ + j] = acc[mi][ni][r] * scale;
            }
}

// ---- softmax over rows of 256; reads fp32, writes bf16 IN PLACE ----
// bf16 row (512B) overwrites the first half of the fp32 row (1KB): per-lane
// reads complete into regs before any write; one wave owns one row.
__global__ __launch_bounds__(256) void softmax256_kernel(float* __restrict__ aw) {
    int wid = threadIdx.x >> 6, lane = threadIdx.x & 63;
    size_t row = (size_t)blockIdx.x * 4 + wid;
    float* p = aw + row * 256;
    float4 v = reinterpret_cast<float4*>(p)[lane];
    float m = fmaxf(fmaxf(v.x, v.y), fmaxf(v.z, v.w));
#pragma unroll
    for (int off = 32; off >= 1; off >>= 1) m = fmaxf(m, __shfl_xor(m, off));
    float e0 = expf(v.x - m), e1 = expf(v.y - m), e2 = expf(v.z - m), e3 = expf(v.w - m);
    float s = e0 + e1 + e2 + e3;
#pragma unroll
    for (int off = 32; off >= 1; off >>= 1) s += __shfl_xor(s, off);
    float inv = 1.0f / s;
    ushort4 ob;
    ob.x = f2bf(e0 * inv); ob.y = f2bf(e1 * inv);
    ob.z = f2bf(e2 * inv); ob.w = f2bf(e3 * inv);
    u16* pb = (u16*)aw + row * 512;
    *reinterpret_cast<ushort4*>(pb + lane * 4) = ob;
}

// ---- Row-attention AP·V v2: block per (r,hn); AP bf16 direct; V^T staged
//      once per j-tile (was 4x); no f2bf anywhere. ----
__global__ __launch_bounds__(256) void row_ctx2_kernel(const u16* __restrict__ apb,
                                                       const u16* __restrict__ v,
                                                       u16* __restrict__ ctx) {
    int r = blockIdx.x;           // 32
    int hn = blockIdx.y;          // 48
    int h = hn >> 2, n = hn & 3;
    __shared__ u16 Vts[64][40];   // Vt[d][j]
    int tid = threadIdx.x, wid = tid >> 6, lane = tid & 63;
    int li = lane & 15, hi = lane >> 4, ko = hi * 8;

    const u16* vpr = v + (size_t)hn * PL_ + (size_t)r * C_ * 64;
    const u16* ap = apb + (size_t)hn * C_ * 512;

    f32x4 acc[4][4] = {};
    for (int j0 = 0; j0 < C_; j0 += 32) {
        U8 vv;
        vv.v = *reinterpret_cast<const short8*>(vpr + (size_t)(j0 + (tid >> 3)) * 64 + (tid & 7) * 8);
#pragma unroll
        for (int u = 0; u < 8; u++) Vts[(tid & 7) * 8 + u][tid >> 3] = vv.u[u];
        __syncthreads();
        short8 af[4], vf[4];
#pragma unroll
        for (int mi = 0; mi < 4; mi++)
            af[mi] = *reinterpret_cast<const short8*>(ap + (size_t)(wid * 64 + mi * 16 + li) * 512 + j0 + ko);
#pragma unroll
        for (int nf = 0; nf < 4; nf++)
            vf[nf] = *reinterpret_cast<const short8*>(&Vts[nf * 16 + li][ko]);
#pragma unroll
        for (int mi = 0; mi < 4; mi++)
#pragma unroll
            for (int nf = 0; nf < 4; nf++)
                acc[mi][nf] = __builtin_amdgcn_mfma_f32_16x16x32_bf16(af[mi], vf[nf], acc[mi][nf], 0, 0, 0);
        __syncthreads();
    }
#pragma unroll
    for (int mi = 0; mi < 4; mi++)
#pragma unroll
        for (int nf = 0; nf < 4; nf++)
#pragma unroll
            for (int rr = 0; rr < 4; rr++) {
                int i = wid * 64 + mi * 16 + hi * 4 + rr;
                int d = nf * 16 + li;
                ctx[((size_t)((r * C_ + i) * N_ + n)) * E_ + h * 64 + d] = f2bf(acc[mi][nf][rr]);
            }
}

// ---- Column attention (planar q/k/v), fused: one wave per (h,c,n) ----
__global__ __launch_bounds__(256) void col_attn_kernel(const u16* __restrict__ q,
                                                       const u16* __restrict__ k,
                                                       const u16* __restrict__ v,
                                                       u16* __restrict__ ctx) {
    __shared__ u16 P[4][32][40];
    int wid = threadIdx.x >> 6, lane = threadIdx.x & 63;
    int g = blockIdx.x * 4 + wid;        // 12288 = H * C * N
    int h = g >> 10;
    int cn = g & 1023;
    int c = cn >> 2, n = cn & 3;
    int li = lane & 15, ko = (lane >> 4) * 8;

    size_t pb = (size_t)(h * 4 + n) * PL_;

    // ---- scores S[i][j] over rows i,j in [0,32), K = d = 64 ----
    f32x4 s[2][2] = {};
#pragma unroll
    for (int d0 = 0; d0 < 64; d0 += 32) {
        short8 aq[2], ak[2];
#pragma unroll
        for (int ia = 0; ia < 2; ia++) {
            size_t oq = pb + ((size_t)((ia * 16 + li) * C_ + c)) * 64 + d0 + ko;
            aq[ia] = *reinterpret_cast<const short8*>(q + oq);
            ak[ia] = *reinterpret_cast<const short8*>(k + oq);
        }
#pragma unroll
        for (int ia = 0; ia < 2; ia++)
#pragma unroll
            for (int jb = 0; jb < 2; jb++)
                s[ia][jb] = __builtin_amdgcn_mfma_f32_16x16x32_bf16(aq[ia], ak[jb], s[ia][jb], 0, 0, 0);
    }
    // ---- softmax over j (32 values per row i) ----
#pragma unroll
    for (int ia = 0; ia < 2; ia++)
#pragma unroll
        for (int rr = 0; rr < 4; rr++) {
            float a0 = s[ia][0][rr] * 0.125f;
            float a1 = s[ia][1][rr] * 0.125f;
            float m = fmaxf(a0, a1);
#pragma unroll
            for (int off = 8; off >= 1; off >>= 1) m = fmaxf(m, __shfl_xor(m, off));
            float e0 = expf(a0 - m), e1 = expf(a1 - m);
            float ss = e0 + e1;
#pragma unroll
            for (int off = 8; off >= 1; off >>= 1) ss += __shfl_xor(ss, off);
            float inv = 1.0f / ss;
            s[ia][0][rr] = e0 * inv;
            s[ia][1][rr] = e1 * inv;
        }
    // ---- P -> LDS (C/D layout -> row-major) ----
#pragma unroll
    for (int ia = 0; ia < 2; ia++)
#pragma unroll
        for (int jb = 0; jb < 2; jb++)
#pragma unroll
            for (int rr = 0; rr < 4; rr++)
                P[wid][ia * 16 + (lane >> 4) * 4 + rr][jb * 16 + li] = f2bf(s[ia][jb][rr]);
    __syncthreads();
    // ---- PV: ctx[i][d] = sum_j P[i][j] * v[j][d] ----
    short8 pa[2];
    pa[0] = *reinterpret_cast<const short8*>(&P[wid][li][ko]);
    pa[1] = *reinterpret_cast<const short8*>(&P[wid][16 + li][ko]);
    f32x4 o[2][4] = {};
#pragma unroll
    for (int df = 0; df < 4; df++) {
        U8 vb;
#pragma unroll
        for (int jj = 0; jj < 8; jj++) {
            int j = (lane >> 4) * 8 + jj;
            vb.u[jj] = v[pb + ((size_t)(j * C_ + c)) * 64 + df * 16 + li];
        }
#pragma unroll
        for (int ia = 0; ia < 2; ia++)
            o[ia][df] = __builtin_amdgcn_mfma_f32_16x16x32_bf16(pa[ia], vb.v, o[ia][df], 0, 0, 0);
    }
#pragma unroll
    for (int ia = 0; ia < 2; ia++)
#pragma unroll
        for (int df = 0; df < 4; df++)
#pragma unroll
            for (int rr = 0; rr < 4; rr++) {
                int i = ia * 16 + (lane >> 4) * 4 + rr;
                int d = df * 16 + li;
                ctx[((size_t)((i * C_ + c) * N_ + n)) * E_ + h * 64 + d] = f2bf(o[ia][df][rr]);
            }
}

// ---------------- launch ----------------
extern "C" void kernel_launch(void* const* d_in, const int* in_sizes, int n_in,
                              void* d_out, int out_size, void* d_ws, size_t ws_size,
                              hipStream_t stream) {
    const float* x     = (const float*)d_in[0];
    const float* ln_w  = (const float*)d_in[1];
    const float* ln_b  = (const float*)d_in[2];
    const float* row_w = (const float*)d_in[3];
    const float* row_b = (const float*)d_in[4];
    const float* col_w = (const float*)d_in[5];
    const float* col_b = (const float*)d_in[6];
    const float* fc1_w = (const float*)d_in[7];
    const float* fc1_b = (const float*)d_in[8];
    const float* fc2_w = (const float*)d_in[9];
    const float* fc2_b = (const float*)d_in[10];
    float* out = (float*)d_out;

    u16* q_bf = (u16*)d_ws;                   // planar [48][32][256][64]
    u16* k_bf = q_bf + TE_;
    u16* v_bf = k_bf + TE_;
    u16* h_bf = v_bf + TE_;                   // token-major; also ctx
    float* aw = (float*)(h_bf + TE_);         // 48*256*256 fp32; softmax downcasts in place
    u16* wrow = (u16*)(aw + (size_t)48 * C_ * C_);
    u16* wcol = wrow + (size_t)4 * E_ * E_;
    u16* wfc1 = wcol + (size_t)4 * E_ * E_;
    u16* wfc2 = wfc1 + (size_t)F_ * E_;
    u16* hid = q_bf;                          // [T][1536] aliases q..k

    const int nW = 4 * E_ * E_;               // 2359296
    cvt_kernel<<<nW / 1024, 256, 0, stream>>>(row_w, wrow, nW);
    cvt_kernel<<<nW / 1024, 256, 0, stream>>>(col_w, wcol, nW);
    cvt_kernel<<<nW / 1024, 256, 0, stream>>>(fc1_w, wfc1, nW);
    cvt_kernel<<<nW / 1024, 256, 0, stream>>>(fc2_w, wfc2, nW);

    // grids: 128 m-tiles (256 rows) x nt_n n-tiles (128 cols)
    const int gQKV = 128 * 18;   // N=2304
    const int gOUT = 128 * 6;    // N=768
    const int gFC1 = 128 * 12;   // N=1536
    const int gFC2 = 128 * 6;    // N=768, K=1536

    // ======== Row self-attention block ========
    ln_kernel<<<T_ / 4, 256, 0, stream>>>(x, ln_w, ln_b, h_bf);
    gemmP<2, false, 24><<<gQKV, 512, 0, stream>>>(h_bf, E_, wrow, E_, row_b, q_bf, E_, nullptr, nullptr, 18);
    row_scores_kernel<<<dim3(16, 48), 256, 0, stream>>>(q_bf, k_bf, aw);
    softmax256_kernel<<<48 * C_ / 4, 256, 0, stream>>>(aw);
    row_ctx2_kernel<<<dim3(32, 48), 256, 0, stream>>>((const u16*)aw, v_bf, h_bf);
    gemmP<1, false, 24><<<gOUT, 512, 0, stream>>>(h_bf, E_, wrow + (size_t)3 * E_ * E_, E_, row_b + 3 * E_, nullptr, E_, out, x, 6);

    // ======== Column self-attention block ========
    ln_kernel<<<T_ / 4, 256, 0, stream>>>(out, ln_w + E_, ln_b + E_, h_bf);
    gemmP<2, false, 24><<<gQKV, 512, 0, stream>>>(h_bf, E_, wcol, E_, col_b, q_bf, E_, nullptr, nullptr, 18);
    col_attn_kernel<<<(H_ * C_ * N_) / 4, 256, 0, stream>>>(q_bf, k_bf, v_bf, h_bf);
    gemmP<1, false, 24><<<gOUT, 512, 0, stream>>>(h_bf, E_, wcol + (size_t)3 * E_ * E_, E_, col_b + 3 * E_, nullptr, E_, out, out, 6);

    // ======== FFN block (two K/N=1536 halves; hidden aliases q..k) ========
    ln_kernel<<<T_ / 4, 256, 0, stream>>>(out, ln_w + 2 * E_, ln_b + 2 * E_, h_bf);
    gemmP<0, true, 24><<<gFC1, 512, 0, stream>>>(h_bf, E_, wfc1, E_, fc1_b, hid, 1536, nullptr, nullptr, 12);
    gemmP<1, false, 48><<<gFC2, 512, 0, stream>>>(hid, 1536, wfc2, F_, fc2_b, nullptr, E_, out, out, 6);
    gemmP<0, true, 24><<<gFC1, 512, 0, stream>>>(h_bf, E_, wfc1 + (size_t)1536 * E_, E_, fc1_b + 1536, hid, 1536, nullptr, nullptr, 12);
    gemmP<1, false, 48><<<gFC2, 512, 0, stream>>>(hid, 1536, wfc2 + 1536, F_, nullptr, nullptr, E_, out, out, 6);
}